// Round 1
// baseline (595.397 us; speedup 1.0000x reference)
//
#include <hip/hip_runtime.h>
#include <math.h>

#define BB  4
#define SQL 2048
#define SKL 2048
#define DD  512
#define MM  8
#define NG  (BB*MM)
#define NTOK (BB*(SQL+SKL))
#define TOK 32
#define SCAP (8u*1024u*1024u)   // cap for S scratch (floats); expected usage ~2.1M
#define SCALE 0.04419417382415922f

// ---------------- routing: f64 accumulation, first-wins argmax ----------------
__global__ void k_route(const float* __restrict__ Q, const float* __restrict__ K,
                        const float* __restrict__ miu,
                        int* __restrict__ aq, int* __restrict__ ak) {
    int g    = blockIdx.x * 4 + (threadIdx.x >> 6);
    int lane = threadIdx.x & 63;
    int b = g >> 12;          // 4096 tokens per batch
    int t = g & 4095;
    const float* x = (t < SQL) ? (Q + (size_t)(b*SQL + t) * DD)
                               : (K + (size_t)(b*SKL + (t - SQL)) * DD);
    double acc[MM];
#pragma unroll
    for (int m = 0; m < MM; ++m) acc[m] = 0.0;
#pragma unroll
    for (int j = 0; j < 8; ++j) {
        int i = j * 64 + lane;
        float xv = x[i];
#pragma unroll
        for (int m = 0; m < MM; ++m) acc[m] += (double)xv * (double)miu[m*DD + i];
    }
#pragma unroll
    for (int m = 0; m < MM; ++m) {
#pragma unroll
        for (int off = 32; off > 0; off >>= 1)
            acc[m] += __shfl_down(acc[m], off);
    }
    if (lane == 0) {
        double best = acc[0]; int bi = 0;
#pragma unroll
        for (int m = 1; m < MM; ++m) if (acc[m] > best) { best = acc[m]; bi = m; }
        if (t < SQL) aq[b*SQL + t] = bi; else ak[b*SKL + (t - SQL)] = bi;
    }
}

// ---------------- stable compaction into per-(b,m) index lists ----------------
__global__ void k_compact(const int* __restrict__ aq, const int* __restrict__ ak,
                          int* __restrict__ qcnt, int* __restrict__ kcnt,
                          int* __restrict__ qlist, int* __restrict__ klist) {
    int idx = blockIdx.x;          // 0..63
    int isK = idx >> 5;
    int g   = idx & 31;
    int b = g >> 3, m = g & 7;
    const int* a = isK ? (ak + b*SKL) : (aq + b*SQL);
    int* list = (isK ? klist : qlist) + g*SQL;
    int lane = threadIdx.x;
    int base = 0;
    for (int c = 0; c < SQL; c += 64) {
        int s = c + lane;
        bool f = (a[s] == m);
        unsigned long long mk = __ballot(f);
        int before = __popcll(mk & ((1ull << lane) - 1ull));
        if (f) list[base + before] = s;
        base += __popcll(mk);
    }
    if (lane == 0) (isK ? kcnt : qcnt)[g] = base;
}

// ---------------- prefix of per-group score sizes ----------------
__global__ void k_soff(const int* __restrict__ qcnt, const int* __restrict__ kcnt,
                       int* __restrict__ soff) {
    if (threadIdx.x == 0) {
        int acc = 0;
        for (int g = 0; g < NG; ++g) { soff[g] = acc; acc += qcnt[g]*kcnt[g]; }
        soff[NG] = acc;
    }
}

// ---------------- grouped expert projection (gelu(x@W + b)) ----------------
__global__ __launch_bounds__(256) void k_proj(
        const float* __restrict__ X, const float* __restrict__ Wall,
        const float* __restrict__ ball, const int* __restrict__ cnt,
        const int* __restrict__ list, float* __restrict__ Y) {
    int g = blockIdx.x;
    int b = g >> 3, m = g & 7;
    int n = cnt[g];
    int t0 = blockIdx.y * TOK;
    if (t0 >= n) return;
    __shared__ float4 xs[TOK][DD/4];
    __shared__ int rows[TOK];
    int tid = threadIdx.x;
    if (tid < TOK) rows[tid] = list[g*SQL + min(t0 + tid, n - 1)];
    __syncthreads();
    const float* Xb = X + (size_t)b * SQL * DD;
    for (int idx = tid; idx < TOK * (DD/4); idx += 256) {
        int i = idx >> 7, q = idx & 127;
        xs[i][q] = ((const float4*)(Xb + (size_t)rows[i] * DD))[q];
    }
    __syncthreads();
    const float* Wm = Wall + (size_t)m * DD * DD;
    float acc0[TOK], acc1[TOK];
#pragma unroll
    for (int i = 0; i < TOK; ++i) { acc0[i] = 0.f; acc1[i] = 0.f; }
    int e0 = tid * 2;
    for (int d4 = 0; d4 < DD; d4 += 4) {
        float2 w0 = *(const float2*)(Wm + (size_t)(d4+0)*DD + e0);
        float2 w1 = *(const float2*)(Wm + (size_t)(d4+1)*DD + e0);
        float2 w2 = *(const float2*)(Wm + (size_t)(d4+2)*DD + e0);
        float2 w3 = *(const float2*)(Wm + (size_t)(d4+3)*DD + e0);
#pragma unroll
        for (int i = 0; i < TOK; ++i) {
            float4 xv = xs[i][d4 >> 2];
            acc0[i] += xv.x*w0.x + xv.y*w1.x + xv.z*w2.x + xv.w*w3.x;
            acc1[i] += xv.x*w0.y + xv.y*w1.y + xv.z*w2.y + xv.w*w3.y;
        }
    }
    float b0 = ball[m*DD + e0], b1 = ball[m*DD + e0 + 1];
    float* Yb = Y + (size_t)b * SQL * DD;
    int nv = min(TOK, n - t0);
    for (int i = 0; i < nv; ++i) {
        float v0 = acc0[i] + b0, v1 = acc1[i] + b1;
        v0 = 0.5f * v0 * (1.0f + erff(v0 * 0.70710678118654752f));
        v1 = 0.5f * v1 * (1.0f + erff(v1 * 0.70710678118654752f));
        float2 o; o.x = v0; o.y = v1;
        *(float2*)(Yb + (size_t)rows[i] * DD + e0) = o;
    }
}

// ---------------- mean of Kp over all keys (fallback value), two-stage ----------------
__global__ void k_meanpart(const float* __restrict__ Kp, float* __restrict__ part) {
    int b = blockIdx.x, ch = blockIdx.y;
    int d = threadIdx.x;
    float a0 = 0.f, a1 = 0.f;
    for (int t = ch*256; t < ch*256 + 256; ++t) {
        const float* row = Kp + ((size_t)(b*SKL) + t) * DD;
        a0 += row[d]; a1 += row[d + 256];
    }
    part[((size_t)(b*8 + ch))*DD + d]       = a0;
    part[((size_t)(b*8 + ch))*DD + d + 256] = a1;
}
__global__ void k_meanfinal(const float* __restrict__ part, float* __restrict__ meanV) {
    int b = blockIdx.x; int d = threadIdx.x;
    float a0 = 0.f, a1 = 0.f;
    for (int ch = 0; ch < 8; ++ch) {
        a0 += part[((size_t)(b*8 + ch))*DD + d];
        a1 += part[((size_t)(b*8 + ch))*DD + d + 256];
    }
    meanV[b*DD + d]       = a0 * (1.0f/SKL);
    meanV[b*DD + d + 256] = a1 * (1.0f/SKL);
}

// ---------------- grouped scores S = (Qp @ Kp^T) * scale ----------------
__global__ __launch_bounds__(256) void k_scores(
        const float* __restrict__ Qp, const float* __restrict__ Kp,
        const int* __restrict__ qcnt, const int* __restrict__ kcnt,
        const int* __restrict__ qlist, const int* __restrict__ klist,
        const int* __restrict__ soff, float* __restrict__ S) {
    int g = blockIdx.x;
    int nq = qcnt[g], nk = kcnt[g];
    int qt = blockIdx.y * 64, kt = blockIdx.z * 64;
    if (qt >= nq || kt >= nk) return;
    int b = g >> 3;
    __shared__ float As[32][68], Bs[32][68];
    __shared__ int qidx[64], kidx[64];
    int tid = threadIdx.x;
    if (tid < 64)       qidx[tid]      = qlist[g*SQL + min(qt + tid, nq - 1)];
    else if (tid < 128) kidx[tid - 64] = klist[g*SKL + min(kt + tid - 64, nk - 1)];
    const float* Qb = Qp + (size_t)b * SQL * DD;
    const float* Kb = Kp + (size_t)b * SKL * DD;
    float acc[4][4] = {};
    int ty = tid >> 4, tx = tid & 15;
    for (int d0 = 0; d0 < DD; d0 += 32) {
        __syncthreads();
        for (int idx = tid; idx < 64*32; idx += 256) {
            int r = idx >> 5, c = idx & 31;
            As[c][r] = Qb[(size_t)qidx[r]*DD + d0 + c];
            Bs[c][r] = Kb[(size_t)kidx[r]*DD + d0 + c];
        }
        __syncthreads();
#pragma unroll
        for (int kk = 0; kk < 32; ++kk) {
            float4 av = *(const float4*)&As[kk][ty << 2];
            float4 bv = *(const float4*)&Bs[kk][tx << 2];
            acc[0][0] += av.x*bv.x; acc[0][1] += av.x*bv.y; acc[0][2] += av.x*bv.z; acc[0][3] += av.x*bv.w;
            acc[1][0] += av.y*bv.x; acc[1][1] += av.y*bv.y; acc[1][2] += av.y*bv.z; acc[1][3] += av.y*bv.w;
            acc[2][0] += av.z*bv.x; acc[2][1] += av.z*bv.y; acc[2][2] += av.z*bv.z; acc[2][3] += av.z*bv.w;
            acc[3][0] += av.w*bv.x; acc[3][1] += av.w*bv.y; acc[3][2] += av.w*bv.z; acc[3][3] += av.w*bv.w;
        }
    }
    int sbase = soff[g];
#pragma unroll
    for (int i = 0; i < 4; ++i) {
        int r = qt + (ty << 2) + i;
        if (r >= nq) continue;
#pragma unroll
        for (int j = 0; j < 4; ++j) {
            int c = kt + (tx << 2) + j;
            if (c < nk) S[(size_t)sbase + (size_t)r*nk + c] = acc[i][j] * SCALE;
        }
    }
}

// ---------------- per-row softmax over group keys (in place) ----------------
__global__ void k_softmax(const int* __restrict__ qcnt, const int* __restrict__ kcnt,
                          const int* __restrict__ soff, float* __restrict__ S) {
    int g = blockIdx.x;
    int nq = qcnt[g], nk = kcnt[g];
    int wid = threadIdx.x >> 6, lane = threadIdx.x & 63;
    int row = blockIdx.y * 16 + wid;
    if (nk == 0 || row >= nq) return;
    float* p = S + (size_t)soff[g] + (size_t)row * nk;
    float mx = -3.4e38f;
    for (int c = lane; c < nk; c += 64) mx = fmaxf(mx, p[c]);
#pragma unroll
    for (int off = 32; off > 0; off >>= 1) mx = fmaxf(mx, __shfl_xor(mx, off));
    float sm = 0.f;
    for (int c = lane; c < nk; c += 64) { float e = expf(p[c] - mx); p[c] = e; sm += e; }
#pragma unroll
    for (int off = 32; off > 0; off >>= 1) sm += __shfl_xor(sm, off);
    float inv = 1.0f / sm;
    for (int c = lane; c < nk; c += 64) p[c] *= inv;
}

// ---------------- PV: O = W @ Kp(group), epilogue += Q ----------------
__global__ __launch_bounds__(256) void k_pv(
        const float* __restrict__ Kp, const float* __restrict__ Q,
        const int* __restrict__ qcnt, const int* __restrict__ kcnt,
        const int* __restrict__ qlist, const int* __restrict__ klist,
        const int* __restrict__ soff, const float* __restrict__ S,
        float* __restrict__ out) {
    int g = blockIdx.x;
    int nq = qcnt[g], nk = kcnt[g];
    int qt = blockIdx.y * 64, dt = blockIdx.z * 64;
    if (nk == 0 || qt >= nq) return;
    int b = g >> 3;
    __shared__ float Ws[32][68];
    __shared__ float Kt[32][64];
    int tid = threadIdx.x;
    int ty = tid >> 4, tx = tid & 15;
    int sbase = soff[g];
    const float* Kb = Kp + (size_t)b * SKL * DD;
    float acc[4][4] = {};
    for (int kk = 0; kk < nk; kk += 32) {
        __syncthreads();
        for (int idx = tid; idx < 64*32; idx += 256) {
            int r = idx >> 5, c = idx & 31;     // r: query row, c: key col
            float w = 0.f;
            if (qt + r < nq && kk + c < nk)
                w = S[(size_t)sbase + (size_t)(qt + r)*nk + kk + c];
            Ws[c][r] = w;
        }
        for (int idx = tid; idx < 32*64; idx += 256) {
            int r = idx >> 6, c = idx & 63;     // r: key row, c: d col
            int kj = klist[g*SKL + min(kk + r, nk - 1)];
            Kt[r][c] = Kb[(size_t)kj*DD + dt + c];
        }
        __syncthreads();
#pragma unroll
        for (int k2 = 0; k2 < 32; ++k2) {
            float4 wv = *(const float4*)&Ws[k2][ty << 2];
            float4 kv = *(const float4*)&Kt[k2][tx << 2];
            acc[0][0] += wv.x*kv.x; acc[0][1] += wv.x*kv.y; acc[0][2] += wv.x*kv.z; acc[0][3] += wv.x*kv.w;
            acc[1][0] += wv.y*kv.x; acc[1][1] += wv.y*kv.y; acc[1][2] += wv.y*kv.z; acc[1][3] += wv.y*kv.w;
            acc[2][0] += wv.z*kv.x; acc[2][1] += wv.z*kv.y; acc[2][2] += wv.z*kv.z; acc[2][3] += wv.z*kv.w;
            acc[3][0] += wv.w*kv.x; acc[3][1] += wv.w*kv.y; acc[3][2] += wv.w*kv.z; acc[3][3] += wv.w*kv.w;
        }
    }
#pragma unroll
    for (int i = 0; i < 4; ++i) {
        int r = qt + (ty << 2) + i;
        if (r >= nq) continue;
        int qrow = qlist[g*SQL + r];
        size_t o = ((size_t)(b*SQL) + qrow) * DD + dt + (tx << 2);
        float4 qv = *(const float4*)(Q + o);
        float4 ov;
        ov.x = acc[i][0] + qv.x; ov.y = acc[i][1] + qv.y;
        ov.z = acc[i][2] + qv.z; ov.w = acc[i][3] + qv.w;
        *(float4*)(out + o) = ov;
    }
}

// ---------------- fallback for groups with no keys: O = mean(Kp) + Q ----------------
__global__ void k_fallback(const float* __restrict__ Q, const float* __restrict__ meanV,
                           const int* __restrict__ qcnt, const int* __restrict__ kcnt,
                           const int* __restrict__ qlist, float* __restrict__ out) {
    int g = blockIdx.x;
    if (kcnt[g] != 0) return;
    int nq = qcnt[g]; int b = g >> 3;
    int r0 = blockIdx.y * 256;
    int rend = min(r0 + 256, nq);
    for (int r = r0; r < rend; ++r) {
        int qrow = qlist[g*SQL + r];
        size_t base = ((size_t)(b*SQL) + qrow) * DD;
        for (int d = threadIdx.x; d < DD; d += 256)
            out[base + d] = meanV[b*DD + d] + Q[base + d];
    }
}

extern "C" void kernel_launch(void* const* d_in, const int* in_sizes, int n_in,
                              void* d_out, int out_size, void* d_ws, size_t ws_size,
                              hipStream_t stream) {
    (void)in_sizes; (void)n_in; (void)out_size; (void)ws_size;
    const float* Q   = (const float*)d_in[0];
    const float* K   = (const float*)d_in[1];
    // d_in[2] (V) is unused: Vp == Kp in the reference.
    const float* miu = (const float*)d_in[3];
    const float* Wq  = (const float*)d_in[4];
    const float* bq  = (const float*)d_in[5];
    const float* Wk  = (const float*)d_in[6];
    const float* bk  = (const float*)d_in[7];
    float* out = (float*)d_out;
    char* ws = (char*)d_ws;

    size_t off = 0;
    auto alloc = [&](size_t bytes) { size_t o = off; off += (bytes + 255) & ~(size_t)255; return o; };
    int*   aq    = (int*)  (ws + alloc((size_t)BB*SQL*4));
    int*   ak    = (int*)  (ws + alloc((size_t)BB*SKL*4));
    int*   qcnt  = (int*)  (ws + alloc(NG*4));
    int*   kcnt  = (int*)  (ws + alloc(NG*4));
    int*   soff  = (int*)  (ws + alloc((NG+1)*4));
    int*   qlist = (int*)  (ws + alloc((size_t)NG*SQL*4));
    int*   klist = (int*)  (ws + alloc((size_t)NG*SKL*4));
    float* Qp    = (float*)(ws + alloc((size_t)BB*SQL*DD*4));
    float* Kp    = (float*)(ws + alloc((size_t)BB*SKL*DD*4));
    float* part  = (float*)(ws + alloc((size_t)BB*8*DD*4));
    float* meanV = (float*)(ws + alloc((size_t)BB*DD*4));
    float* S     = (float*)(ws + alloc((size_t)SCAP*4));

    k_route    <<<NTOK/4, 256, 0, stream>>>(Q, K, miu, aq, ak);
    k_compact  <<<NG*2, 64, 0, stream>>>(aq, ak, qcnt, kcnt, qlist, klist);
    k_soff     <<<1, 64, 0, stream>>>(qcnt, kcnt, soff);
    k_proj     <<<dim3(NG, SQL/TOK), 256, 0, stream>>>(Q, Wq, bq, qcnt, qlist, Qp);
    k_proj     <<<dim3(NG, SKL/TOK), 256, 0, stream>>>(K, Wk, bk, kcnt, klist, Kp);
    k_meanpart <<<dim3(BB, 8), 256, 0, stream>>>(Kp, part);
    k_meanfinal<<<BB, 256, 0, stream>>>(part, meanV);
    k_scores   <<<dim3(NG, 32, 32), 256, 0, stream>>>(Qp, Kp, qcnt, kcnt, qlist, klist, soff, S);
    k_softmax  <<<dim3(NG, 128), 1024, 0, stream>>>(qcnt, kcnt, soff, S);
    k_pv       <<<dim3(NG, 32, 8), 256, 0, stream>>>(Kp, Q, qcnt, kcnt, qlist, klist, soff, S, out);
    k_fallback <<<dim3(NG, 8), 256, 0, stream>>>(Q, meanV, qcnt, kcnt, qlist, out);
}

// Round 2
// 329.605 us; speedup vs baseline: 1.8064x; 1.8064x over previous
//
#include <hip/hip_runtime.h>
#include <hip/hip_bf16.h>
#include <math.h>

#define BB  4
#define SQL 2048
#define SKL 2048
#define DD  512
#define MM  8
#define NG  (BB*MM)
#define NTOK (BB*(SQL+SKL))
#define SCAP (8u*1024u*1024u)   // cap for S scratch (floats); expected usage ~2.1M
#define SCALE 0.04419417382415922f

typedef __attribute__((ext_vector_type(8))) short short8v;
typedef __attribute__((ext_vector_type(4))) float f32x4;

__device__ __forceinline__ ushort f2b(float x) {
    union { __hip_bfloat16 h; ushort u; } cv;
    cv.h = __float2bfloat16(x);
    return cv.u;
}

// ---------------- routing: f64 accumulation, first-wins argmax ----------------
__global__ void k_route(const float* __restrict__ Q, const float* __restrict__ K,
                        const float* __restrict__ miu,
                        int* __restrict__ aq, int* __restrict__ ak) {
    int g    = blockIdx.x * 4 + (threadIdx.x >> 6);
    int lane = threadIdx.x & 63;
    int b = g >> 12;          // 4096 tokens per batch
    int t = g & 4095;
    const float* x = (t < SQL) ? (Q + (size_t)(b*SQL + t) * DD)
                               : (K + (size_t)(b*SKL + (t - SQL)) * DD);
    double acc[MM];
#pragma unroll
    for (int m = 0; m < MM; ++m) acc[m] = 0.0;
#pragma unroll
    for (int j = 0; j < 8; ++j) {
        int i = j * 64 + lane;
        float xv = x[i];
#pragma unroll
        for (int m = 0; m < MM; ++m) acc[m] += (double)xv * (double)miu[m*DD + i];
    }
#pragma unroll
    for (int m = 0; m < MM; ++m) {
#pragma unroll
        for (int off = 32; off > 0; off >>= 1)
            acc[m] += __shfl_down(acc[m], off);
    }
    if (lane == 0) {
        double best = acc[0]; int bi = 0;
#pragma unroll
        for (int m = 1; m < MM; ++m) if (acc[m] > best) { best = acc[m]; bi = m; }
        if (t < SQL) aq[b*SQL + t] = bi; else ak[b*SKL + (t - SQL)] = bi;
    }
}

// ---------------- stable compaction into per-(b,m) index lists ----------------
__global__ void k_compact(const int* __restrict__ aq, const int* __restrict__ ak,
                          int* __restrict__ qcnt, int* __restrict__ kcnt,
                          int* __restrict__ qlist, int* __restrict__ klist) {
    int idx = blockIdx.x;          // 0..63
    int isK = idx >> 5;
    int g   = idx & 31;
    int b = g >> 3, m = g & 7;
    const int* a = isK ? (ak + b*SKL) : (aq + b*SQL);
    int* list = (isK ? klist : qlist) + g*SQL;
    int lane = threadIdx.x;
    int base = 0;
    for (int c = 0; c < SQL; c += 64) {
        int s = c + lane;
        bool f = (a[s] == m);
        unsigned long long mk = __ballot(f);
        int before = __popcll(mk & ((1ull << lane) - 1ull));
        if (f) list[base + before] = s;
        base += __popcll(mk);
    }
    if (lane == 0) (isK ? kcnt : qcnt)[g] = base;
}

// ---------------- prefix of per-group score sizes ----------------
__global__ void k_soff(const int* __restrict__ qcnt, const int* __restrict__ kcnt,
                       int* __restrict__ soff) {
    if (threadIdx.x == 0) {
        int acc = 0;
        for (int g = 0; g < NG; ++g) { soff[g] = acc; acc += qcnt[g]*kcnt[g]; }
        soff[NG] = acc;
    }
}

// ---------------- f32 -> bf16 converts ----------------
__global__ void k_cvtX(const float* __restrict__ Q, const float* __restrict__ K,
                       ushort* __restrict__ Qb, ushort* __restrict__ Kb) {
    const size_t N4 = (size_t)BB * SQL * DD / 4;   // float4 groups per tensor
    size_t i = (size_t)blockIdx.x * blockDim.x + threadIdx.x;
    const float* src; ushort* dst;
    if (i < N4) { src = Q; dst = Qb; }
    else        { src = K; dst = Kb; i -= N4; }
    float4 v = ((const float4*)src)[i];
    ushort4 o;
    o.x = f2b(v.x); o.y = f2b(v.y); o.z = f2b(v.z); o.w = f2b(v.w);
    ((ushort4*)dst)[i] = o;
}

// W[m][d][e] (f32) -> Wt[m][e][d] (bf16), tiled transpose
__global__ void k_cvtW(const float* __restrict__ Wq, const float* __restrict__ Wk,
                       ushort* __restrict__ Wqt, ushort* __restrict__ Wkt) {
    __shared__ float tile[32][33];
    int mm = blockIdx.x; int isK = mm >> 3; int m = mm & 7;
    const float* W = (isK ? Wk : Wq) + (size_t)m * DD * DD;
    ushort* Wt = (isK ? Wkt : Wqt) + (size_t)m * DD * DD;
    int d0 = blockIdx.y * 32, e0 = blockIdx.z * 32;
    int tx = threadIdx.x, ty = threadIdx.y;   // 32 x 8
    for (int i = ty; i < 32; i += 8)
        tile[i][tx] = W[(size_t)(d0 + i) * DD + e0 + tx];
    __syncthreads();
    for (int i = ty; i < 32; i += 8)
        Wt[(size_t)(e0 + i) * DD + d0 + tx] = f2b(tile[tx][i]);
}

// ---------------- grouped expert projection via bf16 MFMA ----------------
// grid (NG*2, 32 token-tiles of 64, 2 col-halves), block 256 (4 waves).
// Each wave: 64 tokens x 64 cols = 4x4 fragments of 16x16x32.
__global__ __launch_bounds__(256) void k_proj_mfma(
        const ushort* __restrict__ Qb, const ushort* __restrict__ Kb,
        const ushort* __restrict__ Wqt, const ushort* __restrict__ Wkt,
        const float* __restrict__ bq, const float* __restrict__ bk,
        const int* __restrict__ qcnt, const int* __restrict__ kcnt,
        const int* __restrict__ qlist, const int* __restrict__ klist,
        float* __restrict__ Qp, float* __restrict__ Kp) {
    int gi = blockIdx.x; int isK = gi >> 5; int g = gi & 31;
    int n = (isK ? kcnt : qcnt)[g];
    int t0 = blockIdx.y * 64;
    if (t0 >= n) return;
    int b = g >> 3, m = g & 7;
    const ushort* Xb = (isK ? Kb : Qb) + (size_t)b * SQL * DD;
    const ushort* Wt = (isK ? Wkt : Wqt) + (size_t)m * DD * DD;
    const float* bias = (isK ? bk : bq) + m * DD;
    const int* list = (isK ? klist : qlist) + g * SQL;
    float* Yb = (isK ? Kp : Qp) + (size_t)b * SQL * DD;

    __shared__ int rows[64];
    int tid = threadIdx.x;
    if (tid < 64) rows[tid] = list[min(t0 + tid, n - 1)];
    __syncthreads();

    int wid = tid >> 6, lane = tid & 63;
    int c0 = blockIdx.z * 256 + wid * 64;
    int lr = lane & 15, lk = (lane >> 4) * 8;

    f32x4 acc[4][4];
#pragma unroll
    for (int t = 0; t < 4; ++t)
#pragma unroll
        for (int c = 0; c < 4; ++c) acc[t][c] = (f32x4){0.f, 0.f, 0.f, 0.f};

    const ushort* arow[4];
#pragma unroll
    for (int t = 0; t < 4; ++t)
        arow[t] = Xb + (size_t)rows[t*16 + lr] * DD + lk;
    const ushort* bcol[4];
#pragma unroll
    for (int c = 0; c < 4; ++c)
        bcol[c] = Wt + (size_t)(c0 + c*16 + lr) * DD + lk;

    for (int d0 = 0; d0 < DD; d0 += 32) {
        short8v a[4], bb[4];
#pragma unroll
        for (int t = 0; t < 4; ++t) a[t]  = *(const short8v*)(arow[t] + d0);
#pragma unroll
        for (int c = 0; c < 4; ++c) bb[c] = *(const short8v*)(bcol[c] + d0);
#pragma unroll
        for (int t = 0; t < 4; ++t)
#pragma unroll
            for (int c = 0; c < 4; ++c)
                acc[t][c] = __builtin_amdgcn_mfma_f32_16x16x32_bf16(a[t], bb[c], acc[t][c], 0, 0, 0);
    }

    float bcache[4];
#pragma unroll
    for (int c = 0; c < 4; ++c) bcache[c] = bias[c0 + c*16 + lr];

    int rb = (lane >> 4) << 2;
#pragma unroll
    for (int t = 0; t < 4; ++t) {
#pragma unroll
        for (int r = 0; r < 4; ++r) {
            int tt = t*16 + rb + r;
            if (t0 + tt >= n) continue;
            size_t ybase = (size_t)rows[tt] * DD;
#pragma unroll
            for (int c = 0; c < 4; ++c) {
                float v = acc[t][c][r] + bcache[c];
                v = 0.5f * v * (1.0f + erff(v * 0.70710678118654752f));
                Yb[ybase + c0 + c*16 + lr] = v;
            }
        }
    }
}

// ---------------- mean of Kp over all keys (fallback value), two-stage ----------------
__global__ void k_meanpart(const float* __restrict__ Kp, float* __restrict__ part) {
    int b = blockIdx.x, ch = blockIdx.y;
    int d = threadIdx.x;
    float a0 = 0.f, a1 = 0.f;
    for (int t = ch*256; t < ch*256 + 256; ++t) {
        const float* row = Kp + ((size_t)(b*SKL) + t) * DD;
        a0 += row[d]; a1 += row[d + 256];
    }
    part[((size_t)(b*8 + ch))*DD + d]       = a0;
    part[((size_t)(b*8 + ch))*DD + d + 256] = a1;
}
__global__ void k_meanfinal(const float* __restrict__ part, float* __restrict__ meanV) {
    int b = blockIdx.x; int d = threadIdx.x;
    float a0 = 0.f, a1 = 0.f;
    for (int ch = 0; ch < 8; ++ch) {
        a0 += part[((size_t)(b*8 + ch))*DD + d];
        a1 += part[((size_t)(b*8 + ch))*DD + d + 256];
    }
    meanV[b*DD + d]       = a0 * (1.0f/SKL);
    meanV[b*DD + d + 256] = a1 * (1.0f/SKL);
}

// ---------------- grouped scores S = (Qp @ Kp^T) * scale ----------------
__global__ __launch_bounds__(256) void k_scores(
        const float* __restrict__ Qp, const float* __restrict__ Kp,
        const int* __restrict__ qcnt, const int* __restrict__ kcnt,
        const int* __restrict__ qlist, const int* __restrict__ klist,
        const int* __restrict__ soff, float* __restrict__ S) {
    int g = blockIdx.x;
    int nq = qcnt[g], nk = kcnt[g];
    int qt = blockIdx.y * 64, kt = blockIdx.z * 64;
    if (qt >= nq || kt >= nk) return;
    int b = g >> 3;
    __shared__ float As[32][68], Bs[32][68];
    __shared__ int qidx[64], kidx[64];
    int tid = threadIdx.x;
    if (tid < 64)       qidx[tid]      = qlist[g*SQL + min(qt + tid, nq - 1)];
    else if (tid < 128) kidx[tid - 64] = klist[g*SKL + min(kt + tid - 64, nk - 1)];
    const float* Qb = Qp + (size_t)b * SQL * DD;
    const float* Kb = Kp + (size_t)b * SKL * DD;
    float acc[4][4] = {};
    int ty = tid >> 4, tx = tid & 15;
    for (int d0 = 0; d0 < DD; d0 += 32) {
        __syncthreads();
        for (int idx = tid; idx < 64*32; idx += 256) {
            int r = idx >> 5, c = idx & 31;
            As[c][r] = Qb[(size_t)qidx[r]*DD + d0 + c];
            Bs[c][r] = Kb[(size_t)kidx[r]*DD + d0 + c];
        }
        __syncthreads();
#pragma unroll
        for (int kk = 0; kk < 32; ++kk) {
            float4 av = *(const float4*)&As[kk][ty << 2];
            float4 bv = *(const float4*)&Bs[kk][tx << 2];
            acc[0][0] += av.x*bv.x; acc[0][1] += av.x*bv.y; acc[0][2] += av.x*bv.z; acc[0][3] += av.x*bv.w;
            acc[1][0] += av.y*bv.x; acc[1][1] += av.y*bv.y; acc[1][2] += av.y*bv.z; acc[1][3] += av.y*bv.w;
            acc[2][0] += av.z*bv.x; acc[2][1] += av.z*bv.y; acc[2][2] += av.z*bv.z; acc[2][3] += av.z*bv.w;
            acc[3][0] += av.w*bv.x; acc[3][1] += av.w*bv.y; acc[3][2] += av.w*bv.z; acc[3][3] += av.w*bv.w;
        }
    }
    int sbase = soff[g];
#pragma unroll
    for (int i = 0; i < 4; ++i) {
        int r = qt + (ty << 2) + i;
        if (r >= nq) continue;
#pragma unroll
        for (int j = 0; j < 4; ++j) {
            int c = kt + (tx << 2) + j;
            if (c < nk) S[(size_t)sbase + (size_t)r*nk + c] = acc[i][j] * SCALE;
        }
    }
}

// ---------------- per-row softmax over group keys (in place) ----------------
__global__ void k_softmax(const int* __restrict__ qcnt, const int* __restrict__ kcnt,
                          const int* __restrict__ soff, float* __restrict__ S) {
    int g = blockIdx.x;
    int nq = qcnt[g], nk = kcnt[g];
    int wid = threadIdx.x >> 6, lane = threadIdx.x & 63;
    int row = blockIdx.y * 16 + wid;
    if (nk == 0 || row >= nq) return;
    float* p = S + (size_t)soff[g] + (size_t)row * nk;
    float mx = -3.4e38f;
    for (int c = lane; c < nk; c += 64) mx = fmaxf(mx, p[c]);
#pragma unroll
    for (int off = 32; off > 0; off >>= 1) mx = fmaxf(mx, __shfl_xor(mx, off));
    float sm = 0.f;
    for (int c = lane; c < nk; c += 64) { float e = expf(p[c] - mx); p[c] = e; sm += e; }
#pragma unroll
    for (int off = 32; off > 0; off >>= 1) sm += __shfl_xor(sm, off);
    float inv = 1.0f / sm;
    for (int c = lane; c < nk; c += 64) p[c] *= inv;
}

// ---------------- PV: O = W @ Kp(group), epilogue += Q ----------------
__global__ __launch_bounds__(256) void k_pv(
        const float* __restrict__ Kp, const float* __restrict__ Q,
        const int* __restrict__ qcnt, const int* __restrict__ kcnt,
        const int* __restrict__ qlist, const int* __restrict__ klist,
        const int* __restrict__ soff, const float* __restrict__ S,
        float* __restrict__ out) {
    int g = blockIdx.x;
    int nq = qcnt[g], nk = kcnt[g];
    int qt = blockIdx.y * 64, dt = blockIdx.z * 64;
    if (nk == 0 || qt >= nq) return;
    int b = g >> 3;
    __shared__ float Ws[32][68];
    __shared__ float Kt[32][64];
    int tid = threadIdx.x;
    int ty = tid >> 4, tx = tid & 15;
    int sbase = soff[g];
    const float* Kb = Kp + (size_t)b * SKL * DD;
    float acc[4][4] = {};
    for (int kk = 0; kk < nk; kk += 32) {
        __syncthreads();
        for (int idx = tid; idx < 64*32; idx += 256) {
            int r = idx >> 5, c = idx & 31;     // r: query row, c: key col
            float w = 0.f;
            if (qt + r < nq && kk + c < nk)
                w = S[(size_t)sbase + (size_t)(qt + r)*nk + kk + c];
            Ws[c][r] = w;
        }
        for (int idx = tid; idx < 32*64; idx += 256) {
            int r = idx >> 6, c = idx & 63;     // r: key row, c: d col
            int kj = klist[g*SKL + min(kk + r, nk - 1)];
            Kt[r][c] = Kb[(size_t)kj*DD + dt + c];
        }
        __syncthreads();
#pragma unroll
        for (int k2 = 0; k2 < 32; ++k2) {
            float4 wv = *(const float4*)&Ws[k2][ty << 2];
            float4 kv = *(const float4*)&Kt[k2][tx << 2];
            acc[0][0] += wv.x*kv.x; acc[0][1] += wv.x*kv.y; acc[0][2] += wv.x*kv.z; acc[0][3] += wv.x*kv.w;
            acc[1][0] += wv.y*kv.x; acc[1][1] += wv.y*kv.y; acc[1][2] += wv.y*kv.z; acc[1][3] += wv.y*kv.w;
            acc[2][0] += wv.z*kv.x; acc[2][1] += wv.z*kv.y; acc[2][2] += wv.z*kv.z; acc[2][3] += wv.z*kv.w;
            acc[3][0] += wv.w*kv.x; acc[3][1] += wv.w*kv.y; acc[3][2] += wv.w*kv.z; acc[3][3] += wv.w*kv.w;
        }
    }
#pragma unroll
    for (int i = 0; i < 4; ++i) {
        int r = qt + (ty << 2) + i;
        if (r >= nq) continue;
        int qrow = qlist[g*SQL + r];
        size_t o = ((size_t)(b*SQL) + qrow) * DD + dt + (tx << 2);
        float4 qv = *(const float4*)(Q + o);
        float4 ov;
        ov.x = acc[i][0] + qv.x; ov.y = acc[i][1] + qv.y;
        ov.z = acc[i][2] + qv.z; ov.w = acc[i][3] + qv.w;
        *(float4*)(out + o) = ov;
    }
}

// ---------------- fallback for groups with no keys: O = mean(Kp) + Q ----------------
__global__ void k_fallback(const float* __restrict__ Q, const float* __restrict__ meanV,
                           const int* __restrict__ qcnt, const int* __restrict__ kcnt,
                           const int* __restrict__ qlist, float* __restrict__ out) {
    int g = blockIdx.x;
    if (kcnt[g] != 0) return;
    int nq = qcnt[g]; int b = g >> 3;
    int r0 = blockIdx.y * 256;
    int rend = min(r0 + 256, nq);
    for (int r = r0; r < rend; ++r) {
        int qrow = qlist[g*SQL + r];
        size_t base = ((size_t)(b*SQL) + qrow) * DD;
        for (int d = threadIdx.x; d < DD; d += 256)
            out[base + d] = meanV[b*DD + d] + Q[base + d];
    }
}

extern "C" void kernel_launch(void* const* d_in, const int* in_sizes, int n_in,
                              void* d_out, int out_size, void* d_ws, size_t ws_size,
                              hipStream_t stream) {
    (void)in_sizes; (void)n_in; (void)out_size; (void)ws_size;
    const float* Q   = (const float*)d_in[0];
    const float* K   = (const float*)d_in[1];
    // d_in[2] (V) is unused: Vp == Kp in the reference.
    const float* miu = (const float*)d_in[3];
    const float* Wq  = (const float*)d_in[4];
    const float* bq  = (const float*)d_in[5];
    const float* Wk  = (const float*)d_in[6];
    const float* bk  = (const float*)d_in[7];
    float* out = (float*)d_out;
    char* ws = (char*)d_ws;

    size_t off = 0;
    auto alloc = [&](size_t bytes) { size_t o = off; off += (bytes + 255) & ~(size_t)255; return o; };
    int*   aq    = (int*)  (ws + alloc((size_t)BB*SQL*4));
    int*   ak    = (int*)  (ws + alloc((size_t)BB*SKL*4));
    int*   qcnt  = (int*)  (ws + alloc(NG*4));
    int*   kcnt  = (int*)  (ws + alloc(NG*4));
    int*   soff  = (int*)  (ws + alloc((NG+1)*4));
    int*   qlist = (int*)  (ws + alloc((size_t)NG*SQL*4));
    int*   klist = (int*)  (ws + alloc((size_t)NG*SKL*4));
    float* Qp    = (float*)(ws + alloc((size_t)BB*SQL*DD*4));
    float* Kp    = (float*)(ws + alloc((size_t)BB*SKL*DD*4));
    float* part  = (float*)(ws + alloc((size_t)BB*8*DD*4));
    float* meanV = (float*)(ws + alloc((size_t)BB*DD*4));
    // S is only live AFTER the bf16 staging buffers are dead -> alias them.
    size_t uoff = alloc((size_t)SCAP*4);
    float* S    = (float*)(ws + uoff);
    ushort* Qb  = (ushort*)(ws + uoff);
    ushort* Kb  = Qb  + (size_t)BB*SQL*DD;
    ushort* Wqt = Kb  + (size_t)BB*SKL*DD;
    ushort* Wkt = Wqt + (size_t)MM*DD*DD;

    k_route    <<<NTOK/4, 256, 0, stream>>>(Q, K, miu, aq, ak);
    k_compact  <<<NG*2, 64, 0, stream>>>(aq, ak, qcnt, kcnt, qlist, klist);
    k_soff     <<<1, 64, 0, stream>>>(qcnt, kcnt, soff);
    k_cvtX     <<<(2*(size_t)BB*SQL*DD/4 + 255)/256, 256, 0, stream>>>(Q, K, Qb, Kb);
    k_cvtW     <<<dim3(16, 16, 16), dim3(32, 8), 0, stream>>>(Wq, Wk, Wqt, Wkt);
    k_proj_mfma<<<dim3(NG*2, 32, 2), 256, 0, stream>>>(Qb, Kb, Wqt, Wkt, bq, bk,
                                                       qcnt, kcnt, qlist, klist, Qp, Kp);
    k_meanpart <<<dim3(BB, 8), 256, 0, stream>>>(Kp, part);
    k_meanfinal<<<BB, 256, 0, stream>>>(part, meanV);
    k_scores   <<<dim3(NG, 32, 32), 256, 0, stream>>>(Qp, Kp, qcnt, kcnt, qlist, klist, soff, S);
    k_softmax  <<<dim3(NG, 128), 1024, 0, stream>>>(qcnt, kcnt, soff, S);
    k_pv       <<<dim3(NG, 32, 8), 256, 0, stream>>>(Kp, Q, qcnt, kcnt, qlist, klist, soff, S, out);
    k_fallback <<<dim3(NG, 8), 256, 0, stream>>>(Q, meanV, qcnt, kcnt, qlist, out);
}

// Round 4
// 216.407 us; speedup vs baseline: 2.7513x; 1.5231x over previous
//
#include <hip/hip_runtime.h>
#include <hip/hip_bf16.h>
#include <math.h>

#define BB  4
#define SQL 2048
#define SKL 2048
#define DD  512
#define MM  8
#define NG  (BB*MM)
#define NTOK (BB*(SQL+SKL))
#define SCAP (8u*1024u*1024u)   // f32 score scratch cap (elements)
#define PCAP (8u*1024u*1024u)   // bf16 prob scratch cap (elements)
#define SCALE 0.04419417382415922f

typedef __attribute__((ext_vector_type(8))) short short8v;
typedef __attribute__((ext_vector_type(4))) float f32x4;

__device__ __forceinline__ ushort f2b(float x) {
    union { __hip_bfloat16 h; ushort u; } cv; cv.h = __float2bfloat16(x); return cv.u;
}
__device__ __forceinline__ float b2f(ushort x) {
    union { ushort u; __hip_bfloat16 h; } cv; cv.u = x; return __bfloat162float(cv.h);
}

// ---------------- routing: f64 accumulation, first-wins argmax ----------------
__global__ void k_route(const float* __restrict__ Q, const float* __restrict__ K,
                        const float* __restrict__ miu,
                        int* __restrict__ aq, int* __restrict__ ak) {
    int g    = blockIdx.x * 4 + (threadIdx.x >> 6);
    int lane = threadIdx.x & 63;
    int b = g >> 12;
    int t = g & 4095;
    const float* x = (t < SQL) ? (Q + (size_t)(b*SQL + t) * DD)
                               : (K + (size_t)(b*SKL + (t - SQL)) * DD);
    double acc[MM];
#pragma unroll
    for (int m = 0; m < MM; ++m) acc[m] = 0.0;
#pragma unroll
    for (int j = 0; j < 8; ++j) {
        int i = j * 64 + lane;
        float xv = x[i];
#pragma unroll
        for (int m = 0; m < MM; ++m) acc[m] += (double)xv * (double)miu[m*DD + i];
    }
#pragma unroll
    for (int m = 0; m < MM; ++m) {
#pragma unroll
        for (int off = 32; off > 0; off >>= 1)
            acc[m] += __shfl_down(acc[m], off);
    }
    if (lane == 0) {
        double best = acc[0]; int bi = 0;
#pragma unroll
        for (int m = 1; m < MM; ++m) if (acc[m] > best) { best = acc[m]; bi = m; }
        if (t < SQL) aq[b*SQL + t] = bi; else ak[b*SKL + (t - SQL)] = bi;
    }
}

// ---------------- stable compaction into per-(b,m) index lists ----------------
__global__ void k_compact(const int* __restrict__ aq, const int* __restrict__ ak,
                          int* __restrict__ qcnt, int* __restrict__ kcnt,
                          int* __restrict__ qlist, int* __restrict__ klist) {
    int idx = blockIdx.x;
    int isK = idx >> 5;
    int g   = idx & 31;
    int b = g >> 3, m = g & 7;
    const int* a = isK ? (ak + b*SKL) : (aq + b*SQL);
    int* list = (isK ? klist : qlist) + g*SQL;
    int lane = threadIdx.x;
    int base = 0;
    for (int c = 0; c < SQL; c += 64) {
        int s = c + lane;
        bool f = (a[s] == m);
        unsigned long long mk = __ballot(f);
        int before = __popcll(mk & ((1ull << lane) - 1ull));
        if (f) list[base + before] = s;
        base += __popcll(mk);
    }
    if (lane == 0) (isK ? kcnt : qcnt)[g] = base;
}

// ---------------- prefix sums: S offsets, P offsets, compacted row offsets ----------------
__global__ void k_soff(const int* __restrict__ qcnt, const int* __restrict__ kcnt,
                       int* __restrict__ soff, int* __restrict__ pboff,
                       int* __restrict__ qoff, int* __restrict__ koff) {
    if (threadIdx.x == 0) {
        int sacc = 0, pacc = 0, qa = 0, ka = 0;
        for (int g = 0; g < NG; ++g) {
            soff[g] = sacc; pboff[g] = pacc; qoff[g] = qa; koff[g] = ka;
            int nq = qcnt[g], nk = kcnt[g];
            int nkp = (nk + 31) & ~31;
            sacc += nq * nk; pacc += nq * nkp; qa += nq; ka += nk;
        }
        soff[NG] = sacc; pboff[NG] = pacc; qoff[NG] = qa; koff[NG] = ka;
    }
}

// W[m][d][e] (f32) -> Wt[m][e][d] (bf16), tiled transpose
__global__ void k_cvtW(const float* __restrict__ Wq, const float* __restrict__ Wk,
                       ushort* __restrict__ Wqt, ushort* __restrict__ Wkt) {
    __shared__ float tile[32][33];
    int mm = blockIdx.x; int isK = mm >> 3; int m = mm & 7;
    const float* W = (isK ? Wk : Wq) + (size_t)m * DD * DD;
    ushort* Wt = (isK ? Wkt : Wqt) + (size_t)m * DD * DD;
    int d0 = blockIdx.y * 32, e0 = blockIdx.z * 32;
    int tx = threadIdx.x, ty = threadIdx.y;
    for (int i = ty; i < 32; i += 8)
        tile[i][tx] = W[(size_t)(d0 + i) * DD + e0 + tx];
    __syncthreads();
    for (int i = ty; i < 32; i += 8)
        Wt[(size_t)(e0 + i) * DD + d0 + tx] = f2b(tile[tx][i]);
}

// ---------------- grouped expert projection via bf16 MFMA -> compacted bf16 out ----------------
__global__ __launch_bounds__(256) void k_proj_mfma(
        const float* __restrict__ Q, const float* __restrict__ K,
        const ushort* __restrict__ Wqt, const ushort* __restrict__ Wkt,
        const float* __restrict__ bq, const float* __restrict__ bk,
        const int* __restrict__ qcnt, const int* __restrict__ kcnt,
        const int* __restrict__ qlist, const int* __restrict__ klist,
        const int* __restrict__ qoff, const int* __restrict__ koff,
        ushort* __restrict__ Qc, ushort* __restrict__ Kc) {
    int gi = blockIdx.x; int isK = gi >> 5; int g = gi & 31;
    int n = (isK ? kcnt : qcnt)[g];
    int t0 = blockIdx.y * 64;
    if (t0 >= n) return;
    int b = g >> 3, m = g & 7;
    const float* Xb = (isK ? K : Q) + (size_t)b * SQL * DD;
    const ushort* Wt = (isK ? Wkt : Wqt) + (size_t)m * DD * DD;
    const float* bias = (isK ? bk : bq) + m * DD;
    const int* list = (isK ? klist : qlist) + g * SQL;
    int obase = (isK ? koff : qoff)[g];
    ushort* Yc = isK ? Kc : Qc;

    __shared__ int rows[64];
    int tid = threadIdx.x;
    if (tid < 64) rows[tid] = list[min(t0 + tid, n - 1)];
    __syncthreads();

    int wid = tid >> 6, lane = tid & 63;
    int c0 = blockIdx.z * 256 + wid * 64;
    int lr = lane & 15, lk = (lane >> 4) * 8;

    f32x4 acc[4][4];
#pragma unroll
    for (int t = 0; t < 4; ++t)
#pragma unroll
        for (int c = 0; c < 4; ++c) acc[t][c] = (f32x4){0.f, 0.f, 0.f, 0.f};

    const float* arow[4];
#pragma unroll
    for (int t = 0; t < 4; ++t)
        arow[t] = Xb + (size_t)rows[t*16 + lr] * DD + lk;
    const ushort* bcol[4];
#pragma unroll
    for (int c = 0; c < 4; ++c)
        bcol[c] = Wt + (size_t)(c0 + c*16 + lr) * DD + lk;

    for (int d0 = 0; d0 < DD; d0 += 32) {
        short8v a[4], bb[4];
#pragma unroll
        for (int t = 0; t < 4; ++t) {
            float4 u0 = *(const float4*)(arow[t] + d0);
            float4 u1 = *(const float4*)(arow[t] + d0 + 4);
            union { short8v v; ushort u[8]; } pk;
            pk.u[0] = f2b(u0.x); pk.u[1] = f2b(u0.y); pk.u[2] = f2b(u0.z); pk.u[3] = f2b(u0.w);
            pk.u[4] = f2b(u1.x); pk.u[5] = f2b(u1.y); pk.u[6] = f2b(u1.z); pk.u[7] = f2b(u1.w);
            a[t] = pk.v;
        }
#pragma unroll
        for (int c = 0; c < 4; ++c) bb[c] = *(const short8v*)(bcol[c] + d0);
#pragma unroll
        for (int t = 0; t < 4; ++t)
#pragma unroll
            for (int c = 0; c < 4; ++c)
                acc[t][c] = __builtin_amdgcn_mfma_f32_16x16x32_bf16(a[t], bb[c], acc[t][c], 0, 0, 0);
    }

    float bcache[4];
#pragma unroll
    for (int c = 0; c < 4; ++c) bcache[c] = bias[c0 + c*16 + lr];

    int rb = (lane >> 4) << 2;
#pragma unroll
    for (int t = 0; t < 4; ++t) {
#pragma unroll
        for (int r = 0; r < 4; ++r) {
            int tt = t*16 + rb + r;
            if (t0 + tt >= n) continue;
            size_t ybase = (size_t)(obase + t0 + tt) * DD;
#pragma unroll
            for (int c = 0; c < 4; ++c) {
                float v = acc[t][c][r] + bcache[c];
                v = 0.5f * v * (1.0f + erff(v * 0.70710678118654752f));
                Yc[ybase + c0 + c*16 + lr] = f2b(v);
            }
        }
    }
}

// ---------------- mean of Kp over all keys (fallback value), two-stage ----------------
__global__ void k_meanpart(const ushort* __restrict__ Kc, const int* __restrict__ koff,
                           float* __restrict__ part) {
    int b = blockIdx.x, ch = blockIdx.y;
    int d = threadIdx.x;
    int base = koff[b*8];
    float a0 = 0.f, a1 = 0.f;
    for (int t = ch*256; t < ch*256 + 256; ++t) {
        const ushort* row = Kc + (size_t)(base + t) * DD;
        a0 += b2f(row[d]); a1 += b2f(row[d + 256]);
    }
    part[((size_t)(b*8 + ch))*DD + d]       = a0;
    part[((size_t)(b*8 + ch))*DD + d + 256] = a1;
}
__global__ void k_meanfinal(const float* __restrict__ part, float* __restrict__ meanV) {
    int b = blockIdx.x; int d = threadIdx.x;
    float a0 = 0.f, a1 = 0.f;
    for (int ch = 0; ch < 8; ++ch) {
        a0 += part[((size_t)(b*8 + ch))*DD + d];
        a1 += part[((size_t)(b*8 + ch))*DD + d + 256];
    }
    meanV[b*DD + d]       = a0 * (1.0f/SKL);
    meanV[b*DD + d + 256] = a1 * (1.0f/SKL);
}

// ---------------- grouped scores S = (Qc @ Kc^T) * scale, bf16 MFMA ----------------
// block: 4 waves (2x2), tile 128q x 128k, frag loads straight from compacted rows.
__global__ __launch_bounds__(256) void k_scores_mfma(
        const ushort* __restrict__ Qc, const ushort* __restrict__ Kc,
        const int* __restrict__ qcnt, const int* __restrict__ kcnt,
        const int* __restrict__ qoff, const int* __restrict__ koff,
        const int* __restrict__ soff, float* __restrict__ S) {
    int g = blockIdx.x;
    int nq = qcnt[g], nk = kcnt[g];
    int qt = blockIdx.y * 128, kt = blockIdx.z * 128;
    if (qt >= nq || kt >= nk) return;
    int tid = threadIdx.x, wid = tid >> 6, lane = tid & 63;
    int wr = wid >> 1, wc = wid & 1;
    int lr = lane & 15, lk = (lane >> 4) * 8;
    int qb = qoff[g], kb = koff[g];

    const ushort* ap[4];
#pragma unroll
    for (int t = 0; t < 4; ++t)
        ap[t] = Qc + (size_t)(qb + min(qt + wr*64 + t*16 + lr, nq - 1)) * DD + lk;
    const ushort* bp[4];
#pragma unroll
    for (int c = 0; c < 4; ++c)
        bp[c] = Kc + (size_t)(kb + min(kt + wc*64 + c*16 + lr, nk - 1)) * DD + lk;

    f32x4 acc[4][4];
#pragma unroll
    for (int t = 0; t < 4; ++t)
#pragma unroll
        for (int c = 0; c < 4; ++c) acc[t][c] = (f32x4){0.f, 0.f, 0.f, 0.f};

    for (int d0 = 0; d0 < DD; d0 += 32) {
        short8v a[4], bb[4];
#pragma unroll
        for (int t = 0; t < 4; ++t) a[t]  = *(const short8v*)(ap[t] + d0);
#pragma unroll
        for (int c = 0; c < 4; ++c) bb[c] = *(const short8v*)(bp[c] + d0);
#pragma unroll
        for (int t = 0; t < 4; ++t)
#pragma unroll
            for (int c = 0; c < 4; ++c)
                acc[t][c] = __builtin_amdgcn_mfma_f32_16x16x32_bf16(a[t], bb[c], acc[t][c], 0, 0, 0);
    }

    int sbase = soff[g];
    int rb = (lane >> 4) << 2;
#pragma unroll
    for (int t = 0; t < 4; ++t) {
#pragma unroll
        for (int r = 0; r < 4; ++r) {
            int gr = qt + wr*64 + t*16 + rb + r;
            if (gr >= nq) continue;
#pragma unroll
            for (int c = 0; c < 4; ++c) {
                int gc = kt + wc*64 + c*16 + lr;
                if (gc < nk) S[(size_t)sbase + (size_t)gr*nk + gc] = acc[t][c][r] * SCALE;
            }
        }
    }
}

// ---------------- softmax rows -> bf16 probs with rows padded to mult of 32 ----------------
__global__ void k_softmax(const int* __restrict__ qcnt, const int* __restrict__ kcnt,
                          const int* __restrict__ soff, const int* __restrict__ pboff,
                          float* __restrict__ S, ushort* __restrict__ Pb) {
    int g = blockIdx.x;
    int nq = qcnt[g], nk = kcnt[g];
    int wid = threadIdx.x >> 6, lane = threadIdx.x & 63;
    int row = blockIdx.y * 16 + wid;
    if (nk == 0 || row >= nq) return;
    int nkp = (nk + 31) & ~31;
    float* p = S + (size_t)soff[g] + (size_t)row * nk;
    ushort* pr = Pb + (size_t)pboff[g] + (size_t)row * nkp;
    float mx = -3.4e38f;
    for (int c = lane; c < nk; c += 64) mx = fmaxf(mx, p[c]);
#pragma unroll
    for (int off = 32; off > 0; off >>= 1) mx = fmaxf(mx, __shfl_xor(mx, off));
    float sm = 0.f;
    for (int c = lane; c < nk; c += 64) { float e = expf(p[c] - mx); p[c] = e; sm += e; }
#pragma unroll
    for (int off = 32; off > 0; off >>= 1) sm += __shfl_xor(sm, off);
    float inv = 1.0f / sm;
    for (int c = lane; c < nkp; c += 64) {
        float v = (c < nk) ? p[c] * inv : 0.f;
        pr[c] = f2b(v);
    }
}

// ---------------- PV: O = P @ Kc(group) via bf16 MFMA, epilogue += Q ----------------
// block: 4 waves (2x2), tile 128q x 128d. A = Pb rows (key-contiguous).
// B = Kc^T fragments via 8 strided ushort loads (Kc tile is L1/L2 resident).
__global__ __launch_bounds__(256) void k_pv_mfma(
        const ushort* __restrict__ Pb, const ushort* __restrict__ Kc,
        const float* __restrict__ Q,
        const int* __restrict__ qcnt, const int* __restrict__ kcnt,
        const int* __restrict__ koff, const int* __restrict__ pboff,
        const int* __restrict__ qlist, float* __restrict__ out) {
    int g = blockIdx.x;
    int nq = qcnt[g], nk = kcnt[g];
    int qt = blockIdx.y * 128, dt = blockIdx.z * 128;
    if (nk == 0 || qt >= nq) return;
    int b = g >> 3;
    int tid = threadIdx.x, wid = tid >> 6, lane = tid & 63;
    int wr = wid >> 1, wc = wid & 1;
    int lr = lane & 15, lk = (lane >> 4) * 8;
    int nkp = (nk + 31) & ~31;
    int kb = koff[g];

    const ushort* ap[4];
#pragma unroll
    for (int t = 0; t < 4; ++t)
        ap[t] = Pb + (size_t)pboff[g] + (size_t)min(qt + wr*64 + t*16 + lr, nq - 1) * nkp + lk;
    int dcol[4];
#pragma unroll
    for (int c = 0; c < 4; ++c) dcol[c] = dt + wc*64 + c*16 + lr;

    f32x4 acc[4][4];
#pragma unroll
    for (int t = 0; t < 4; ++t)
#pragma unroll
        for (int c = 0; c < 4; ++c) acc[t][c] = (f32x4){0.f, 0.f, 0.f, 0.f};

    for (int kk = 0; kk < nk; kk += 32) {
        short8v a[4];
#pragma unroll
        for (int t = 0; t < 4; ++t) a[t] = *(const short8v*)(ap[t] + kk);
        const ushort* krow[8];
#pragma unroll
        for (int j = 0; j < 8; ++j)
            krow[j] = Kc + (size_t)(kb + min(kk + lk + j, nk - 1)) * DD;
        short8v bb[4];
#pragma unroll
        for (int c = 0; c < 4; ++c) {
            union { short8v v; ushort u[8]; } pk;
#pragma unroll
            for (int j = 0; j < 8; ++j) pk.u[j] = krow[j][dcol[c]];
            bb[c] = pk.v;
        }
#pragma unroll
        for (int t = 0; t < 4; ++t)
#pragma unroll
            for (int c = 0; c < 4; ++c)
                acc[t][c] = __builtin_amdgcn_mfma_f32_16x16x32_bf16(a[t], bb[c], acc[t][c], 0, 0, 0);
    }

    int rb = (lane >> 4) << 2;
#pragma unroll
    for (int t = 0; t < 4; ++t) {
#pragma unroll
        for (int r = 0; r < 4; ++r) {
            int gr = qt + wr*64 + t*16 + rb + r;
            if (gr >= nq) continue;
            int qrow = qlist[g*SQL + gr];
            size_t obase = ((size_t)(b*SQL) + qrow) * DD;
#pragma unroll
            for (int c = 0; c < 4; ++c) {
                size_t o = obase + dcol[c];
                out[o] = acc[t][c][r] + Q[o];
            }
        }
    }
}

// ---------------- fallback for groups with no keys: O = mean(Kp) + Q ----------------
__global__ void k_fallback(const float* __restrict__ Q, const float* __restrict__ meanV,
                           const int* __restrict__ qcnt, const int* __restrict__ kcnt,
                           const int* __restrict__ qlist, float* __restrict__ out) {
    int g = blockIdx.x;
    if (kcnt[g] != 0) return;
    int nq = qcnt[g]; int b = g >> 3;
    int r0 = blockIdx.y * 256;
    int rend = min(r0 + 256, nq);
    for (int r = r0; r < rend; ++r) {
        int qrow = qlist[g*SQL + r];
        size_t base = ((size_t)(b*SQL) + qrow) * DD;
        for (int d = threadIdx.x; d < DD; d += 256)
            out[base + d] = meanV[b*DD + d] + Q[base + d];
    }
}

extern "C" void kernel_launch(void* const* d_in, const int* in_sizes, int n_in,
                              void* d_out, int out_size, void* d_ws, size_t ws_size,
                              hipStream_t stream) {
    (void)in_sizes; (void)n_in; (void)out_size; (void)ws_size;
    const float* Q   = (const float*)d_in[0];
    const float* K   = (const float*)d_in[1];
    // d_in[2] (V) unused: Vp == Kp in the reference.
    const float* miu = (const float*)d_in[3];
    const float* Wq  = (const float*)d_in[4];
    const float* bq  = (const float*)d_in[5];
    const float* Wk  = (const float*)d_in[6];
    const float* bk  = (const float*)d_in[7];
    float* out = (float*)d_out;
    char* ws = (char*)d_ws;

    size_t off = 0;
    auto alloc = [&](size_t bytes) { size_t o = off; off += (bytes + 255) & ~(size_t)255; return o; };
    int*   aq    = (int*)  (ws + alloc((size_t)BB*SQL*4));
    int*   ak    = (int*)  (ws + alloc((size_t)BB*SKL*4));
    int*   qcnt  = (int*)  (ws + alloc(NG*4));
    int*   kcnt  = (int*)  (ws + alloc(NG*4));
    int*   soff  = (int*)  (ws + alloc((NG+1)*4));
    int*   pboff = (int*)  (ws + alloc((NG+1)*4));
    int*   qoff  = (int*)  (ws + alloc((NG+1)*4));
    int*   koff  = (int*)  (ws + alloc((NG+1)*4));
    int*   qlist = (int*)  (ws + alloc((size_t)NG*SQL*4));
    int*   klist = (int*)  (ws + alloc((size_t)NG*SKL*4));
    float* part  = (float*)(ws + alloc((size_t)BB*8*DD*4));
    float* meanV = (float*)(ws + alloc((size_t)BB*DD*4));
    ushort* Qc   = (ushort*)(ws + alloc((size_t)BB*SQL*DD*2));
    ushort* Kc   = (ushort*)(ws + alloc((size_t)BB*SKL*DD*2));
    ushort* Pb   = (ushort*)(ws + alloc((size_t)PCAP*2));
    // S (f32) is live only after proj; alias it over the bf16 W staging.
    size_t uoff = alloc((size_t)SCAP*4);
    float* S    = (float*)(ws + uoff);
    ushort* Wqt = (ushort*)(ws + uoff);
    ushort* Wkt = Wqt + (size_t)MM*DD*DD;

    k_route     <<<NTOK/4, 256, 0, stream>>>(Q, K, miu, aq, ak);
    k_compact   <<<NG*2, 64, 0, stream>>>(aq, ak, qcnt, kcnt, qlist, klist);
    k_soff      <<<1, 64, 0, stream>>>(qcnt, kcnt, soff, pboff, qoff, koff);
    k_cvtW      <<<dim3(16, 16, 16), dim3(32, 8), 0, stream>>>(Wq, Wk, Wqt, Wkt);
    k_proj_mfma <<<dim3(NG*2, 32, 2), 256, 0, stream>>>(Q, K, Wqt, Wkt, bq, bk,
                                                        qcnt, kcnt, qlist, klist, qoff, koff, Qc, Kc);
    k_meanpart  <<<dim3(BB, 8), 256, 0, stream>>>(Kc, koff, part);
    k_meanfinal <<<BB, 256, 0, stream>>>(part, meanV);
    k_scores_mfma<<<dim3(NG, 16, 16), 256, 0, stream>>>(Qc, Kc, qcnt, kcnt, qoff, koff, soff, S);
    k_softmax   <<<dim3(NG, 128), 1024, 0, stream>>>(qcnt, kcnt, soff, pboff, S, Pb);
    k_pv_mfma   <<<dim3(NG, 16, 4), 256, 0, stream>>>(Pb, Kc, Q, qcnt, kcnt, koff, pboff, qlist, out);
    k_fallback  <<<dim3(NG, 8), 256, 0, stream>>>(Q, meanV, qcnt, kcnt, qlist, out);
}

// Round 5
// 215.486 us; speedup vs baseline: 2.7630x; 1.0043x over previous
//
#include <hip/hip_runtime.h>
#include <hip/hip_bf16.h>
#include <math.h>

#define BB  4
#define SQL 2048
#define SKL 2048
#define DD  512
#define MM  8
#define NG  (BB*MM)
#define NTOK (BB*(SQL+SKL))
#define SCAP (8u*1024u*1024u)   // f32 score scratch cap (elements)
#define PCAP (8u*1024u*1024u)   // bf16 prob scratch cap (elements)
#define KTCAP ((size_t)DD*9216) // bf16 KcT cap (elements): DD * (8192 + 32*31 pad)
#define PROJCAP 512
#define SCCAP   6144
#define PVCAP   256
#define SCALE 0.04419417382415922f

typedef __attribute__((ext_vector_type(8))) short short8v;
typedef __attribute__((ext_vector_type(4))) float f32x4;

__device__ __forceinline__ ushort f2b(float x) {
    union { __hip_bfloat16 h; ushort u; } cv; cv.h = __float2bfloat16(x); return cv.u;
}
__device__ __forceinline__ float b2f(ushort x) {
    union { ushort u; __hip_bfloat16 h; } cv; cv.u = x; return __bfloat162float(cv.h);
}
__device__ __forceinline__ float gelu_exact(float v) {
    return 0.5f * v * (1.0f + erff(v * 0.70710678118654752f));
}

// ---------------- routing: f64 accumulation, first-wins argmax; also emits bf16 Q/K ----------------
__global__ void k_route(const float* __restrict__ Q, const float* __restrict__ K,
                        const float* __restrict__ miu,
                        int* __restrict__ aq, int* __restrict__ ak,
                        ushort* __restrict__ Qb16, ushort* __restrict__ Kb16) {
    int g    = blockIdx.x * 4 + (threadIdx.x >> 6);
    int lane = threadIdx.x & 63;
    int b = g >> 12;
    int t = g & 4095;
    bool isQ = (t < SQL);
    size_t rowoff = isQ ? (size_t)(b*SQL + t) * DD : (size_t)(b*SKL + (t - SQL)) * DD;
    const float* x = (isQ ? Q : K) + rowoff;
    ushort* yb = (isQ ? Qb16 : Kb16) + rowoff;
    double acc[MM];
#pragma unroll
    for (int m = 0; m < MM; ++m) acc[m] = 0.0;
#pragma unroll
    for (int j = 0; j < 8; ++j) {
        int i = j * 64 + lane;
        float xv = x[i];
        yb[i] = f2b(xv);
#pragma unroll
        for (int m = 0; m < MM; ++m) acc[m] += (double)xv * (double)miu[m*DD + i];
    }
#pragma unroll
    for (int m = 0; m < MM; ++m) {
#pragma unroll
        for (int off = 32; off > 0; off >>= 1)
            acc[m] += __shfl_down(acc[m], off);
    }
    if (lane == 0) {
        double best = acc[0]; int bi = 0;
#pragma unroll
        for (int m = 1; m < MM; ++m) if (acc[m] > best) { best = acc[m]; bi = m; }
        if (isQ) aq[b*SQL + t] = bi; else ak[b*SKL + (t - SQL)] = bi;
    }
}

// ---------------- stable compaction into per-(b,m) index lists ----------------
__global__ void k_compact(const int* __restrict__ aq, const int* __restrict__ ak,
                          int* __restrict__ qcnt, int* __restrict__ kcnt,
                          int* __restrict__ qlist, int* __restrict__ klist) {
    int idx = blockIdx.x;
    int isK = idx >> 5;
    int g   = idx & 31;
    int b = g >> 3, m = g & 7;
    const int* a = isK ? (ak + b*SKL) : (aq + b*SQL);
    int* list = (isK ? klist : qlist) + g*SQL;
    int lane = threadIdx.x;
    int base = 0;
    for (int c = 0; c < SQL; c += 64) {
        int s = c + lane;
        bool f = (a[s] == m);
        unsigned long long mk = __ballot(f);
        int before = __popcll(mk & ((1ull << lane) - 1ull));
        if (f) list[base + before] = s;
        base += __popcll(mk);
    }
    if (lane == 0) (isK ? kcnt : qcnt)[g] = base;
}

// ---------------- offsets + compact tile work-lists ----------------
__global__ void k_soff(const int* __restrict__ qcnt, const int* __restrict__ kcnt,
                       int* __restrict__ soff, int* __restrict__ pboff,
                       int* __restrict__ qoff, int* __restrict__ koff,
                       int* __restrict__ tkoff, int* __restrict__ counts,
                       int* __restrict__ projl, int* __restrict__ scl,
                       int* __restrict__ pvl) {
    __shared__ int pbase[64], sbase[32], pvbase[32];
    int lane = threadIdx.x;
    if (lane == 0) {
        int sacc = 0, pacc = 0, qa = 0, ka = 0, ta = 0;
        for (int g = 0; g < NG; ++g) {
            soff[g] = sacc; pboff[g] = pacc; qoff[g] = qa; koff[g] = ka; tkoff[g] = ta;
            int nq = qcnt[g], nk = kcnt[g];
            int nkp = (nk + 31) & ~31;
            sacc += nq * nk; pacc += nq * nkp; qa += nq; ka += nk; ta += DD * nkp;
        }
        soff[NG] = sacc; pboff[NG] = pacc; qoff[NG] = qa; koff[NG] = ka; tkoff[NG] = ta;
        int pj = 0, sc = 0, pv = 0;
        for (int sg = 0; sg < 64; ++sg) {
            int n = (sg >= 32 ? kcnt : qcnt)[sg & 31];
            pbase[sg] = pj; pj += (n + 63) >> 6;
        }
        for (int g = 0; g < NG; ++g) {
            int nq = qcnt[g], nk = kcnt[g];
            sbase[g] = sc; pvbase[g] = pv;
            if (nq > 0 && nk > 0) {
                sc += ((nq + 63) >> 6) * ((nk + 63) >> 6);
                pv += (nq + 63) >> 6;
            }
        }
        counts[0] = pj; counts[1] = sc; counts[2] = pv;
    }
    __syncthreads();
    {   // proj tiles: one (side,g) per lane
        int sg = lane;
        int side = sg >> 5, g = sg & 31;
        int n = (side ? kcnt : qcnt)[g];
        int ntile = (n + 63) >> 6;
        int base = pbase[sg];
        for (int ty = 0; ty < ntile; ++ty)
            projl[base + ty] = (side << 11) | (g << 6) | ty;
    }
    if (lane < 32) {   // scores + pv tiles: one g per lane
        int g = lane;
        int nq = qcnt[g], nk = kcnt[g];
        if (nq > 0 && nk > 0) {
            int nqt = (nq + 63) >> 6, nkt = (nk + 63) >> 6;
            int idx = sbase[g];
            for (int qy = 0; qy < nqt; ++qy)
                for (int ky = 0; ky < nkt; ++ky)
                    scl[idx++] = (g << 10) | (qy << 5) | ky;
            int pidx = pvbase[g];
            for (int qy = 0; qy < nqt; ++qy)
                pvl[pidx++] = (g << 5) | qy;
        }
    }
}

// W[m][d][e] (f32) -> Wt[m][e][d] (bf16), tiled transpose
__global__ void k_cvtW(const float* __restrict__ Wq, const float* __restrict__ Wk,
                       ushort* __restrict__ Wqt, ushort* __restrict__ Wkt) {
    __shared__ float tile[32][33];
    int mm = blockIdx.x; int isK = mm >> 3; int m = mm & 7;
    const float* W = (isK ? Wk : Wq) + (size_t)m * DD * DD;
    ushort* Wt = (isK ? Wkt : Wqt) + (size_t)m * DD * DD;
    int d0 = blockIdx.y * 32, e0 = blockIdx.z * 32;
    int tx = threadIdx.x, ty = threadIdx.y;
    for (int i = ty; i < 32; i += 8)
        tile[i][tx] = W[(size_t)(d0 + i) * DD + e0 + tx];
    __syncthreads();
    for (int i = ty; i < 32; i += 8)
        Wt[(size_t)(e0 + i) * DD + d0 + tx] = f2b(tile[tx][i]);
}

// ---------------- grouped expert projection, bf16 MFMA, list-driven ----------------
// block: 4 waves, tile 64 tokens x 256 cols (blockIdx.y selects col half of 512).
// Q-side writes Qc (pre-scaled by SCALE); K-side writes Kc and transposed KcT.
__global__ __launch_bounds__(256) void k_proj_mfma(
        const ushort* __restrict__ Qb16, const ushort* __restrict__ Kb16,
        const ushort* __restrict__ Wqt, const ushort* __restrict__ Wkt,
        const float* __restrict__ bq, const float* __restrict__ bk,
        const int* __restrict__ qcnt, const int* __restrict__ kcnt,
        const int* __restrict__ qlist, const int* __restrict__ klist,
        const int* __restrict__ qoff, const int* __restrict__ koff,
        const int* __restrict__ tkoff, const int* __restrict__ counts,
        const int* __restrict__ projl,
        ushort* __restrict__ Qc, ushort* __restrict__ Kc, ushort* __restrict__ KcT) {
    __shared__ int rows[64];
    int tid = threadIdx.x;
    int wid = tid >> 6, lane = tid & 63;
    int lr = lane & 15, lk = (lane >> 4) * 8;
    int cnt = counts[0];
    for (int slot = blockIdx.x; slot < cnt; slot += gridDim.x) {
        int e = projl[slot];
        int isK = (e >> 11) & 1, g = (e >> 6) & 31, ty = e & 63;
        int t0 = ty * 64;
        int n = (isK ? kcnt : qcnt)[g];
        int b = g >> 3, m = g & 7;
        const ushort* Xb = (isK ? Kb16 : Qb16) + (size_t)b * SQL * DD;
        const ushort* Wt = (isK ? Wkt : Wqt) + (size_t)m * DD * DD;
        const float* bias = (isK ? bk : bq) + m * DD;
        const int* list = (isK ? klist : qlist) + g * SQL;
        int obase = (isK ? koff : qoff)[g];
        ushort* Yc = isK ? Kc : Qc;

        __syncthreads();
        if (tid < 64) rows[tid] = list[min(t0 + tid, n - 1)];
        __syncthreads();

        int c0 = blockIdx.y * 256 + wid * 64;

        const ushort* arow[4];
#pragma unroll
        for (int t = 0; t < 4; ++t)
            arow[t] = Xb + (size_t)rows[t*16 + lr] * DD + lk;
        const ushort* bcol[4];
#pragma unroll
        for (int c = 0; c < 4; ++c)
            bcol[c] = Wt + (size_t)(c0 + c*16 + lr) * DD + lk;

        f32x4 acc[4][4];
#pragma unroll
        for (int t = 0; t < 4; ++t)
#pragma unroll
            for (int c = 0; c < 4; ++c) acc[t][c] = (f32x4){0.f, 0.f, 0.f, 0.f};

        short8v a[4], bb[4], an[4], bn[4];
#pragma unroll
        for (int t = 0; t < 4; ++t) a[t]  = *(const short8v*)(arow[t]);
#pragma unroll
        for (int c = 0; c < 4; ++c) bb[c] = *(const short8v*)(bcol[c]);
        for (int d0 = 0; d0 < DD; d0 += 32) {
            int dn = d0 + 32;
            if (dn < DD) {
#pragma unroll
                for (int t = 0; t < 4; ++t) an[t] = *(const short8v*)(arow[t] + dn);
#pragma unroll
                for (int c = 0; c < 4; ++c) bn[c] = *(const short8v*)(bcol[c] + dn);
            }
#pragma unroll
            for (int t = 0; t < 4; ++t)
#pragma unroll
                for (int c = 0; c < 4; ++c)
                    acc[t][c] = __builtin_amdgcn_mfma_f32_16x16x32_bf16(a[t], bb[c], acc[t][c], 0, 0, 0);
#pragma unroll
            for (int t = 0; t < 4; ++t) a[t] = an[t];
#pragma unroll
            for (int c = 0; c < 4; ++c) bb[c] = bn[c];
        }

        float bcache[4];
#pragma unroll
        for (int c = 0; c < 4; ++c) bcache[c] = bias[c0 + c*16 + lr];

        int rb = (lane >> 4) << 2;
        int nk = kcnt[g];
        int nkp = (nk + 31) & ~31;
        int tk = tkoff[g];
#pragma unroll
        for (int t = 0; t < 4; ++t) {
            int kbase = t0 + t*16 + rb;      // group-row index of r=0
#pragma unroll
            for (int c = 0; c < 4; ++c) {
                int col = c0 + c*16 + lr;
                float v[4];
#pragma unroll
                for (int r = 0; r < 4; ++r) v[r] = gelu_exact(acc[t][c][r] + bcache[c]);
                if (!isK) {
#pragma unroll
                    for (int r = 0; r < 4; ++r)
                        if (kbase + r < n)
                            Yc[(size_t)(obase + kbase + r) * DD + col] = f2b(v[r] * SCALE);
                } else {
#pragma unroll
                    for (int r = 0; r < 4; ++r)
                        if (kbase + r < n)
                            Yc[(size_t)(obase + kbase + r) * DD + col] = f2b(v[r]);
                    size_t taddr = (size_t)tk + (size_t)col * nkp + kbase;
                    if (kbase + 3 < n) {
                        ushort4 o; o.x = f2b(v[0]); o.y = f2b(v[1]); o.z = f2b(v[2]); o.w = f2b(v[3]);
                        *(ushort4*)(KcT + taddr) = o;
                    } else {
#pragma unroll
                        for (int r = 0; r < 4; ++r)
                            if (kbase + r < n) KcT[taddr + r] = f2b(v[r]);
                    }
                }
            }
        }
    }
}

// ---------------- mean of Kp over all keys (fallback value), two-stage ----------------
__global__ void k_meanpart(const ushort* __restrict__ Kc, const int* __restrict__ koff,
                           float* __restrict__ part) {
    int b = blockIdx.x, ch = blockIdx.y;
    int d = threadIdx.x;
    int base = koff[b*8];
    float a0 = 0.f, a1 = 0.f;
    for (int t = ch*256; t < ch*256 + 256; ++t) {
        const ushort* row = Kc + (size_t)(base + t) * DD;
        a0 += b2f(row[d]); a1 += b2f(row[d + 256]);
    }
    part[((size_t)(b*8 + ch))*DD + d]       = a0;
    part[((size_t)(b*8 + ch))*DD + d + 256] = a1;
}
__global__ void k_meanfinal(const float* __restrict__ part, float* __restrict__ meanV) {
    int b = blockIdx.x; int d = threadIdx.x;
    float a0 = 0.f, a1 = 0.f;
    for (int ch = 0; ch < 8; ++ch) {
        a0 += part[((size_t)(b*8 + ch))*DD + d];
        a1 += part[((size_t)(b*8 + ch))*DD + d + 256];
    }
    meanV[b*DD + d]       = a0 * (1.0f/SKL);
    meanV[b*DD + d + 256] = a1 * (1.0f/SKL);
}

// ---------------- grouped scores S = Qc @ Kc^T (scale pre-folded into Qc) ----------------
// list-driven, block tile 64q x 64k, 4 waves 2x2, wave 32x32 (2x2 frags).
__global__ __launch_bounds__(256) void k_scores_mfma(
        const ushort* __restrict__ Qc, const ushort* __restrict__ Kc,
        const int* __restrict__ qcnt, const int* __restrict__ kcnt,
        const int* __restrict__ qoff, const int* __restrict__ koff,
        const int* __restrict__ soff, const int* __restrict__ counts,
        const int* __restrict__ scl, float* __restrict__ S) {
    int tid = threadIdx.x, wid = tid >> 6, lane = tid & 63;
    int wr = wid >> 1, wc = wid & 1;
    int lr = lane & 15, lk = (lane >> 4) * 8;
    int cnt = counts[1];
    for (int slot = blockIdx.x; slot < cnt; slot += gridDim.x) {
        int e = scl[slot];
        int g = (e >> 10) & 31, qt = ((e >> 5) & 31) * 64, kt = (e & 31) * 64;
        int nq = qcnt[g], nk = kcnt[g];
        int qb = qoff[g], kb = koff[g];

        const ushort* ap[2];
#pragma unroll
        for (int t = 0; t < 2; ++t)
            ap[t] = Qc + (size_t)(qb + min(qt + wr*32 + t*16 + lr, nq - 1)) * DD + lk;
        const ushort* bp[2];
#pragma unroll
        for (int c = 0; c < 2; ++c)
            bp[c] = Kc + (size_t)(kb + min(kt + wc*32 + c*16 + lr, nk - 1)) * DD + lk;

        f32x4 acc[2][2];
#pragma unroll
        for (int t = 0; t < 2; ++t)
#pragma unroll
            for (int c = 0; c < 2; ++c) acc[t][c] = (f32x4){0.f, 0.f, 0.f, 0.f};

        short8v a[2], bb[2], an[2], bn[2];
#pragma unroll
        for (int t = 0; t < 2; ++t) a[t]  = *(const short8v*)(ap[t]);
#pragma unroll
        for (int c = 0; c < 2; ++c) bb[c] = *(const short8v*)(bp[c]);
        for (int d0 = 0; d0 < DD; d0 += 32) {
            int dn = d0 + 32;
            if (dn < DD) {
#pragma unroll
                for (int t = 0; t < 2; ++t) an[t] = *(const short8v*)(ap[t] + dn);
#pragma unroll
                for (int c = 0; c < 2; ++c) bn[c] = *(const short8v*)(bp[c] + dn);
            }
#pragma unroll
            for (int t = 0; t < 2; ++t)
#pragma unroll
                for (int c = 0; c < 2; ++c)
                    acc[t][c] = __builtin_amdgcn_mfma_f32_16x16x32_bf16(a[t], bb[c], acc[t][c], 0, 0, 0);
#pragma unroll
            for (int t = 0; t < 2; ++t) a[t] = an[t];
#pragma unroll
            for (int c = 0; c < 2; ++c) bb[c] = bn[c];
        }

        int sbase = soff[g];
        int rb = (lane >> 4) << 2;
#pragma unroll
        for (int t = 0; t < 2; ++t) {
#pragma unroll
            for (int r = 0; r < 4; ++r) {
                int gr = qt + wr*32 + t*16 + rb + r;
                if (gr >= nq) continue;
#pragma unroll
                for (int c = 0; c < 2; ++c) {
                    int gc = kt + wc*32 + c*16 + lr;
                    if (gc < nk) S[(size_t)sbase + (size_t)gr*nk + gc] = acc[t][c][r];
                }
            }
        }
    }
}

// ---------------- softmax rows -> bf16 probs, rows padded to mult of 32 ----------------
__global__ void k_softmax(const int* __restrict__ qcnt, const int* __restrict__ kcnt,
                          const int* __restrict__ soff, const int* __restrict__ pboff,
                          float* __restrict__ S, ushort* __restrict__ Pb) {
    int g = blockIdx.x;
    int nq = qcnt[g], nk = kcnt[g];
    int wid = threadIdx.x >> 6, lane = threadIdx.x & 63;
    int row = blockIdx.y * 16 + wid;
    if (nk == 0 || row >= nq) return;
    int nkp = (nk + 31) & ~31;
    float* p = S + (size_t)soff[g] + (size_t)row * nk;
    ushort* pr = Pb + (size_t)pboff[g] + (size_t)row * nkp;
    float mx = -3.4e38f;
    for (int c = lane; c < nk; c += 64) mx = fmaxf(mx, p[c]);
#pragma unroll
    for (int off = 32; off > 0; off >>= 1) mx = fmaxf(mx, __shfl_xor(mx, off));
    float sm = 0.f;
    for (int c = lane; c < nk; c += 64) { float e = expf(p[c] - mx); p[c] = e; sm += e; }
#pragma unroll
    for (int off = 32; off > 0; off >>= 1) sm += __shfl_xor(sm, off);
    float inv = 1.0f / sm;
    for (int c = lane; c < nkp; c += 64) {
        float v = (c < nk) ? p[c] * inv : 0.f;
        pr[c] = f2b(v);
    }
}

// ---------------- PV: O = P @ Kc via KcT, bf16 MFMA, epilogue += Q ----------------
// list-driven over (g, 64-row q-tile); blockIdx.y picks 128-col d-tile.
// 4 waves 2x2: wave 32q x 64d (2x4 frags). Both operands contiguous 16B loads.
__global__ __launch_bounds__(256) void k_pv_mfma(
        const ushort* __restrict__ Pb, const ushort* __restrict__ KcT,
        const float* __restrict__ Q,
        const int* __restrict__ qcnt, const int* __restrict__ kcnt,
        const int* __restrict__ tkoff, const int* __restrict__ pboff,
        const int* __restrict__ qlist, const int* __restrict__ counts,
        const int* __restrict__ pvl, float* __restrict__ out) {
    int tid = threadIdx.x, wid = tid >> 6, lane = tid & 63;
    int wr = wid >> 1, wc = wid & 1;
    int lr = lane & 15, lk = (lane >> 4) * 8;
    int cnt = counts[2];
    for (int slot = blockIdx.x; slot < cnt; slot += gridDim.x) {
        int e = pvl[slot];
        int g = e >> 5, qt = (e & 31) * 64;
        int nq = qcnt[g], nk = kcnt[g];
        int b = g >> 3;
        int nkp = (nk + 31) & ~31;
        int tk = tkoff[g], pbase = pboff[g];
        int dt = blockIdx.y * 128;

        const ushort* ap[2];
#pragma unroll
        for (int t = 0; t < 2; ++t)
            ap[t] = Pb + (size_t)pbase + (size_t)min(qt + wr*32 + t*16 + lr, nq - 1) * nkp + lk;
        int dcol[4];
        const ushort* bp[4];
#pragma unroll
        for (int c = 0; c < 4; ++c) {
            dcol[c] = dt + wc*64 + c*16 + lr;
            bp[c] = KcT + (size_t)tk + (size_t)dcol[c] * nkp + lk;
        }

        f32x4 acc[2][4];
#pragma unroll
        for (int t = 0; t < 2; ++t)
#pragma unroll
            for (int c = 0; c < 4; ++c) acc[t][c] = (f32x4){0.f, 0.f, 0.f, 0.f};

        for (int kk = 0; kk < nk; kk += 32) {
            short8v a[2], bb[4];
#pragma unroll
            for (int t = 0; t < 2; ++t) a[t] = *(const short8v*)(ap[t] + kk);
#pragma unroll
            for (int c = 0; c < 4; ++c) bb[c] = *(const short8v*)(bp[c] + kk);
#pragma unroll
            for (int t = 0; t < 2; ++t)
#pragma unroll
                for (int c = 0; c < 4; ++c)
                    acc[t][c] = __builtin_amdgcn_mfma_f32_16x16x32_bf16(a[t], bb[c], acc[t][c], 0, 0, 0);
        }

        int rb = (lane >> 4) << 2;
#pragma unroll
        for (int t = 0; t < 2; ++t) {
#pragma unroll
            for (int r = 0; r < 4; ++r) {
                int gr = qt + wr*32 + t*16 + rb + r;
                if (gr >= nq) continue;
                int qrow = qlist[g*SQL + gr];
                size_t obase = ((size_t)(b*SQL) + qrow) * DD;
#pragma unroll
                for (int c = 0; c < 4; ++c) {
                    size_t o = obase + dcol[c];
                    out[o] = acc[t][c][r] + Q[o];
                }
            }
        }
    }
}

// ---------------- fallback for groups with no keys: O = mean(Kp) + Q ----------------
__global__ void k_fallback(const float* __restrict__ Q, const float* __restrict__ meanV,
                           const int* __restrict__ qcnt, const int* __restrict__ kcnt,
                           const int* __restrict__ qlist, float* __restrict__ out) {
    int g = blockIdx.x;
    if (kcnt[g] != 0) return;
    int nq = qcnt[g]; int b = g >> 3;
    int r0 = blockIdx.y * 256;
    int rend = min(r0 + 256, nq);
    for (int r = r0; r < rend; ++r) {
        int qrow = qlist[g*SQL + r];
        size_t base = ((size_t)(b*SQL) + qrow) * DD;
        for (int d = threadIdx.x; d < DD; d += 256)
            out[base + d] = meanV[b*DD + d] + Q[base + d];
    }
}

extern "C" void kernel_launch(void* const* d_in, const int* in_sizes, int n_in,
                              void* d_out, int out_size, void* d_ws, size_t ws_size,
                              hipStream_t stream) {
    (void)in_sizes; (void)n_in; (void)out_size; (void)ws_size;
    const float* Q   = (const float*)d_in[0];
    const float* K   = (const float*)d_in[1];
    // d_in[2] (V) unused: Vp == Kp in the reference.
    const float* miu = (const float*)d_in[3];
    const float* Wq  = (const float*)d_in[4];
    const float* bq  = (const float*)d_in[5];
    const float* Wk  = (const float*)d_in[6];
    const float* bk  = (const float*)d_in[7];
    float* out = (float*)d_out;
    char* ws = (char*)d_ws;

    size_t off = 0;
    auto alloc = [&](size_t bytes) { size_t o = off; off += (bytes + 255) & ~(size_t)255; return o; };
    int*   aq     = (int*)  (ws + alloc((size_t)BB*SQL*4));
    int*   ak     = (int*)  (ws + alloc((size_t)BB*SKL*4));
    int*   qcnt   = (int*)  (ws + alloc(NG*4));
    int*   kcnt   = (int*)  (ws + alloc(NG*4));
    int*   soff   = (int*)  (ws + alloc((NG+1)*4));
    int*   pboff  = (int*)  (ws + alloc((NG+1)*4));
    int*   qoff   = (int*)  (ws + alloc((NG+1)*4));
    int*   koff   = (int*)  (ws + alloc((NG+1)*4));
    int*   tkoff  = (int*)  (ws + alloc((NG+1)*4));
    int*   counts = (int*)  (ws + alloc(16*4));
    int*   projl  = (int*)  (ws + alloc(PROJCAP*4));
    int*   scl    = (int*)  (ws + alloc(SCCAP*4));
    int*   pvl    = (int*)  (ws + alloc(PVCAP*4));
    int*   qlist  = (int*)  (ws + alloc((size_t)NG*SQL*4));
    int*   klist  = (int*)  (ws + alloc((size_t)NG*SKL*4));
    float* part   = (float*)(ws + alloc((size_t)BB*8*DD*4));
    float* meanV  = (float*)(ws + alloc((size_t)BB*DD*4));
    ushort* Qc    = (ushort*)(ws + alloc((size_t)BB*SQL*DD*2));
    ushort* Kc    = (ushort*)(ws + alloc((size_t)BB*SKL*DD*2));
    ushort* KcT   = (ushort*)(ws + alloc(KTCAP*2));
    ushort* Pb    = (ushort*)(ws + alloc((size_t)PCAP*2));
    // Union region: bf16 staging (Wqt/Wkt/Qb16/Kb16, dead after proj) then S (f32).
    size_t uoff = alloc((size_t)SCAP*4);
    float* S     = (float*)(ws + uoff);
    ushort* Wqt  = (ushort*)(ws + uoff);
    ushort* Wkt  = Wqt  + (size_t)MM*DD*DD;
    ushort* Qb16 = Wkt  + (size_t)MM*DD*DD;
    ushort* Kb16 = Qb16 + (size_t)BB*SQL*DD;

    k_route     <<<NTOK/4, 256, 0, stream>>>(Q, K, miu, aq, ak, Qb16, Kb16);
    k_compact   <<<NG*2, 64, 0, stream>>>(aq, ak, qcnt, kcnt, qlist, klist);
    k_soff      <<<1, 64, 0, stream>>>(qcnt, kcnt, soff, pboff, qoff, koff, tkoff,
                                       counts, projl, scl, pvl);
    k_cvtW      <<<dim3(16, 16, 16), dim3(32, 8), 0, stream>>>(Wq, Wk, Wqt, Wkt);
    k_proj_mfma <<<dim3(512, 2), 256, 0, stream>>>(Qb16, Kb16, Wqt, Wkt, bq, bk,
                                                   qcnt, kcnt, qlist, klist, qoff, koff,
                                                   tkoff, counts, projl, Qc, Kc, KcT);
    k_meanpart  <<<dim3(BB, 8), 256, 0, stream>>>(Kc, koff, part);
    k_meanfinal <<<BB, 256, 0, stream>>>(part, meanV);
    k_scores_mfma<<<1024, 256, 0, stream>>>(Qc, Kc, qcnt, kcnt, qoff, koff, soff,
                                            counts, scl, S);
    k_softmax   <<<dim3(NG, 128), 1024, 0, stream>>>(qcnt, kcnt, soff, pboff, S, Pb);
    k_pv_mfma   <<<dim3(256, 4), 256, 0, stream>>>(Pb, KcT, Q, qcnt, kcnt, tkoff, pboff,
                                                   qlist, counts, pvl, out);
    k_fallback  <<<dim3(NG, 8), 256, 0, stream>>>(Q, meanV, qcnt, kcnt, qlist, out);
}

// Round 6
// 195.517 us; speedup vs baseline: 3.0452x; 1.1021x over previous
//
#include <hip/hip_runtime.h>
#include <hip/hip_bf16.h>
#include <math.h>

#define BB  4
#define SQL 2048
#define SKL 2048
#define DD  512
#define MM  8
#define NG  (BB*MM)
#define NTOK (BB*(SQL+SKL))
#define SCAP (8u*1024u*1024u)   // f32 score scratch cap (elements) == 32 MB union region
#define PCAP (8u*1024u*1024u)   // bf16 prob scratch cap (elements)
#define KTCAP ((size_t)DD*9216) // bf16 KcT cap (elements)
#define PROJCAP 512
#define SCCAP   6144
#define PVCAP   256
#define SCALE 0.04419417382415922f

typedef __attribute__((ext_vector_type(8))) short short8v;
typedef __attribute__((ext_vector_type(4))) float f32x4;

__device__ __forceinline__ ushort f2b(float x) {
    union { __hip_bfloat16 h; ushort u; } cv; cv.h = __float2bfloat16(x); return cv.u;
}
__device__ __forceinline__ float b2f(ushort x) {
    union { ushort u; __hip_bfloat16 h; } cv; cv.u = x; return __bfloat162float(cv.h);
}
__device__ __forceinline__ float gelu_exact(float v) {
    return 0.5f * v * (1.0f + erff(v * 0.70710678118654752f));
}
__device__ __forceinline__ void gload16(const ushort* g, ushort* l) {
    __builtin_amdgcn_global_load_lds(
        (const __attribute__((address_space(1))) void*)g,
        (__attribute__((address_space(3))) void*)l, 16, 0, 0);
}

// ---------------- routing: f64 accumulation, first-wins argmax ----------------
__global__ void k_route(const float* __restrict__ Q, const float* __restrict__ K,
                        const float* __restrict__ miu,
                        int* __restrict__ aq, int* __restrict__ ak) {
    int g    = blockIdx.x * 4 + (threadIdx.x >> 6);
    int lane = threadIdx.x & 63;
    int b = g >> 12;
    int t = g & 4095;
    const float* x = (t < SQL) ? (Q + (size_t)(b*SQL + t) * DD)
                               : (K + (size_t)(b*SKL + (t - SQL)) * DD);
    double acc[MM];
#pragma unroll
    for (int m = 0; m < MM; ++m) acc[m] = 0.0;
#pragma unroll
    for (int j = 0; j < 8; ++j) {
        int i = j * 64 + lane;
        float xv = x[i];
#pragma unroll
        for (int m = 0; m < MM; ++m) acc[m] += (double)xv * (double)miu[m*DD + i];
    }
#pragma unroll
    for (int m = 0; m < MM; ++m) {
#pragma unroll
        for (int off = 32; off > 0; off >>= 1)
            acc[m] += __shfl_down(acc[m], off);
    }
    if (lane == 0) {
        double best = acc[0]; int bi = 0;
#pragma unroll
        for (int m = 1; m < MM; ++m) if (acc[m] > best) { best = acc[m]; bi = m; }
        if (t < SQL) aq[b*SQL + t] = bi; else ak[b*SKL + (t - SQL)] = bi;
    }
}

// ---------------- stable compaction into per-(b,m) index lists ----------------
__global__ void k_compact(const int* __restrict__ aq, const int* __restrict__ ak,
                          int* __restrict__ qcnt, int* __restrict__ kcnt,
                          int* __restrict__ qlist, int* __restrict__ klist) {
    int idx = blockIdx.x;
    int isK = idx >> 5;
    int g   = idx & 31;
    int b = g >> 3, m = g & 7;
    const int* a = isK ? (ak + b*SKL) : (aq + b*SQL);
    int* list = (isK ? klist : qlist) + g*SQL;
    int lane = threadIdx.x;
    int base = 0;
    for (int c = 0; c < SQL; c += 64) {
        int s = c + lane;
        bool f = (a[s] == m);
        unsigned long long mk = __ballot(f);
        int before = __popcll(mk & ((1ull << lane) - 1ull));
        if (f) list[base + before] = s;
        base += __popcll(mk);
    }
    if (lane == 0) (isK ? kcnt : qcnt)[g] = base;
}

// ---------------- offsets + compact tile work-lists ----------------
__global__ void k_soff(const int* __restrict__ qcnt, const int* __restrict__ kcnt,
                       int* __restrict__ soff, int* __restrict__ pboff,
                       int* __restrict__ qoff, int* __restrict__ koff,
                       int* __restrict__ tkoff, int* __restrict__ counts,
                       int* __restrict__ projl, int* __restrict__ scl,
                       int* __restrict__ pvl) {
    __shared__ int pbase[64], sbase[32], pvbase[32];
    int lane = threadIdx.x;
    if (lane == 0) {
        int sacc = 0, pacc = 0, qa = 0, ka = 0, ta = 0;
        for (int g = 0; g < NG; ++g) {
            soff[g] = sacc; pboff[g] = pacc; qoff[g] = qa; koff[g] = ka; tkoff[g] = ta;
            int nq = qcnt[g], nk = kcnt[g];
            int nkp = (nk + 31) & ~31;
            sacc += nq * nk; pacc += nq * nkp; qa += nq; ka += nk; ta += DD * nkp;
        }
        soff[NG] = sacc; pboff[NG] = pacc; qoff[NG] = qa; koff[NG] = ka; tkoff[NG] = ta;
        int pj = 0, sc = 0, pv = 0;
        for (int sg = 0; sg < 64; ++sg) {
            int n = (sg >= 32 ? kcnt : qcnt)[sg & 31];
            pbase[sg] = pj; pj += (n + 127) >> 7;     // 128-token proj tiles
        }
        for (int g = 0; g < NG; ++g) {
            int nq = qcnt[g], nk = kcnt[g];
            sbase[g] = sc; pvbase[g] = pv;
            if (nq > 0 && nk > 0) {
                sc += ((nq + 63) >> 6) * ((nk + 63) >> 6);
                pv += (nq + 63) >> 6;
            }
        }
        counts[0] = pj; counts[1] = sc; counts[2] = pv;
    }
    __syncthreads();
    {   // proj tiles: one (side,g) per lane
        int sg = lane;
        int side = sg >> 5, g = sg & 31;
        int n = (side ? kcnt : qcnt)[g];
        int ntile = (n + 127) >> 7;
        int base = pbase[sg];
        for (int ty = 0; ty < ntile; ++ty)
            projl[base + ty] = (side << 11) | (g << 6) | ty;
    }
    if (lane < 32) {   // scores + pv tiles: one g per lane
        int g = lane;
        int nq = qcnt[g], nk = kcnt[g];
        if (nq > 0 && nk > 0) {
            int nqt = (nq + 63) >> 6, nkt = (nk + 63) >> 6;
            int idx = sbase[g];
            for (int qy = 0; qy < nqt; ++qy)
                for (int ky = 0; ky < nkt; ++ky)
                    scl[idx++] = (g << 10) | (qy << 5) | ky;
            int pidx = pvbase[g];
            for (int qy = 0; qy < nqt; ++qy)
                pvl[pidx++] = (g << 5) | qy;
        }
    }
}

// W[m][d][e] (f32) -> Wt[m][e][d] (bf16), tiled transpose
__global__ void k_cvtW(const float* __restrict__ Wq, const float* __restrict__ Wk,
                       ushort* __restrict__ Wqt, ushort* __restrict__ Wkt) {
    __shared__ float tile[32][33];
    int mm = blockIdx.x; int isK = mm >> 3; int m = mm & 7;
    const float* W = (isK ? Wk : Wq) + (size_t)m * DD * DD;
    ushort* Wt = (isK ? Wkt : Wqt) + (size_t)m * DD * DD;
    int d0 = blockIdx.y * 32, e0 = blockIdx.z * 32;
    int tx = threadIdx.x, ty = threadIdx.y;
    for (int i = ty; i < 32; i += 8)
        tile[i][tx] = W[(size_t)(d0 + i) * DD + e0 + tx];
    __syncthreads();
    for (int i = ty; i < 32; i += 8)
        Wt[(size_t)(e0 + i) * DD + d0 + tx] = f2b(tile[tx][i]);
}

// ---------------- gather: compacted group-ordered bf16 token rows ----------------
// one wave per row; lane covers 8 contiguous elems (float4 x2 -> ushort8).
__global__ void k_gather(const float* __restrict__ Q, const float* __restrict__ K,
                         const int* __restrict__ qcnt, const int* __restrict__ kcnt,
                         const int* __restrict__ qlist, const int* __restrict__ klist,
                         const int* __restrict__ qoff, const int* __restrict__ koff,
                         ushort* __restrict__ XcQ, ushort* __restrict__ XcK) {
    int sg = blockIdx.x; int isK = sg >> 5, g = sg & 31;
    int n = (isK ? kcnt : qcnt)[g];
    int wid = threadIdx.x >> 6, lane = threadIdx.x & 63;
    int row0 = blockIdx.y * 16 + wid * 4;
    if (row0 >= n) return;
    int b = g >> 3;
    const int* list = (isK ? klist : qlist) + g*SQL;
    const float* src = (isK ? K : Q) + (size_t)b * SQL * DD;
    ushort* dst = (isK ? XcK : XcQ) + (size_t)((isK ? koff : qoff)[g]) * DD;
#pragma unroll
    for (int rr = 0; rr < 4; ++rr) {
        int row = row0 + rr;
        if (row >= n) break;
        int tok = list[row];
        const float* s = src + (size_t)tok * DD + lane*8;
        float4 v0 = *(const float4*)(s);
        float4 v1 = *(const float4*)(s + 4);
        union { short8v v; ushort u[8]; } pk;
        pk.u[0] = f2b(v0.x); pk.u[1] = f2b(v0.y); pk.u[2] = f2b(v0.z); pk.u[3] = f2b(v0.w);
        pk.u[4] = f2b(v1.x); pk.u[5] = f2b(v1.y); pk.u[6] = f2b(v1.z); pk.u[7] = f2b(v1.w);
        *(short8v*)(dst + (size_t)row * DD + lane*8) = pk.v;
    }
}

// ---------------- grouped expert projection: canonical LDS-staged bf16 MFMA GEMM ----------------
// list-driven 128-token tiles; blockIdx.y = 128-col tile (4 of them).
// block 256 thr = 4 waves (2x2), wave tile 64x64 (4x4 frags 16x16x32), BK=64,
// single-buffered 32KB LDS, global_load_lds width-16 staging (m97 structure).
__global__ __launch_bounds__(256) void k_proj_mfma(
        const ushort* __restrict__ XcQ, const ushort* __restrict__ XcK,
        const ushort* __restrict__ Wqt, const ushort* __restrict__ Wkt,
        const float* __restrict__ bq, const float* __restrict__ bk,
        const int* __restrict__ qcnt, const int* __restrict__ kcnt,
        const int* __restrict__ qoff, const int* __restrict__ koff,
        const int* __restrict__ tkoff, const int* __restrict__ counts,
        const int* __restrict__ projl,
        ushort* __restrict__ Qc, ushort* __restrict__ Kc, ushort* __restrict__ KcT) {
    __shared__ ushort lds[16384];            // As[128][64] | Bs[128][64]
    ushort* As = lds;
    ushort* Bs = lds + 8192;
    int tid = threadIdx.x;
    int wid = tid >> 6, lane = tid & 63;
    int wr = wid >> 1, wc = wid & 1;
    int lr = lane & 15;
    int lk8 = (lane >> 4) << 3;              // 0,8,16,24 (ushorts)
    int c0 = blockIdx.y * 128;
    int glq = (lane >> 3);                   // stage: row-within-chunk
    int glc = (lane & 7) << 3;               // stage: col (ushorts)
    int cnt = counts[0];

    for (int slot = blockIdx.x; slot < cnt; slot += gridDim.x) {
        int e = projl[slot];
        int isK = (e >> 11) & 1, g = (e >> 6) & 31, ty = e & 63;
        int n = (isK ? kcnt : qcnt)[g];
        int obase = (isK ? koff : qoff)[g];
        int m = g & 7;
        const ushort* X = isK ? XcK : XcQ;
        const ushort* Wt = (isK ? Wkt : Wqt) + (size_t)m * DD * DD;
        const float* bias = (isK ? bk : bq) + m * DD;
        int row0 = obase + ty * 128;

        f32x4 acc[4][4];
#pragma unroll
        for (int t = 0; t < 4; ++t)
#pragma unroll
            for (int c = 0; c < 4; ++c) acc[t][c] = (f32x4){0.f, 0.f, 0.f, 0.f};

        for (int kt = 0; kt < 8; ++kt) {
            int d0 = kt * 64;
            __syncthreads();                 // prev compute done before overwrite
#pragma unroll
            for (int j0 = 0; j0 < 4; ++j0) {
                int j = wid + j0 * 4;        // chunk 0..15
                int rA = min(row0 + j*8 + glq, BB*SQL - 1);
                gload16(X + (size_t)rA * DD + d0 + glc, As + j*512);
                int rB = c0 + j*8 + glq;
                gload16(Wt + (size_t)rB * DD + d0 + glc, Bs + j*512);
            }
            __syncthreads();                 // drains vmcnt before barrier
#pragma unroll
            for (int kk = 0; kk < 2; ++kk) {
                short8v a[4], bb[4];
#pragma unroll
                for (int t = 0; t < 4; ++t)
                    a[t] = *(const short8v*)(As + (wr*64 + t*16 + lr)*64 + kk*32 + lk8);
#pragma unroll
                for (int c = 0; c < 4; ++c)
                    bb[c] = *(const short8v*)(Bs + (wc*64 + c*16 + lr)*64 + kk*32 + lk8);
#pragma unroll
                for (int t = 0; t < 4; ++t)
#pragma unroll
                    for (int c = 0; c < 4; ++c)
                        acc[t][c] = __builtin_amdgcn_mfma_f32_16x16x32_bf16(a[t], bb[c], acc[t][c], 0, 0, 0);
            }
        }

        float bcache[4];
#pragma unroll
        for (int c = 0; c < 4; ++c) bcache[c] = bias[c0 + wc*64 + c*16 + lr];

        int rb = (lane >> 4) << 2;
        int nk2 = kcnt[g];
        int nkp = (nk2 + 31) & ~31;
        int tk = tkoff[g];
        ushort* Yc = isK ? Kc : Qc;
#pragma unroll
        for (int t = 0; t < 4; ++t) {
            int grow = ty*128 + wr*64 + t*16 + rb;   // group-relative row of r=0
#pragma unroll
            for (int c = 0; c < 4; ++c) {
                int col = c0 + wc*64 + c*16 + lr;
                float v[4];
#pragma unroll
                for (int r = 0; r < 4; ++r) v[r] = gelu_exact(acc[t][c][r] + bcache[c]);
                if (!isK) {
#pragma unroll
                    for (int r = 0; r < 4; ++r)
                        if (grow + r < n)
                            Yc[(size_t)(obase + grow + r) * DD + col] = f2b(v[r] * SCALE);
                } else {
#pragma unroll
                    for (int r = 0; r < 4; ++r)
                        if (grow + r < n)
                            Yc[(size_t)(obase + grow + r) * DD + col] = f2b(v[r]);
                    size_t taddr = (size_t)tk + (size_t)col * nkp + grow;
                    if (grow + 3 < n) {
                        ushort4 o; o.x = f2b(v[0]); o.y = f2b(v[1]); o.z = f2b(v[2]); o.w = f2b(v[3]);
                        *(ushort4*)(KcT + taddr) = o;
                    } else {
#pragma unroll
                        for (int r = 0; r < 4; ++r)
                            if (grow + r < n) KcT[taddr + r] = f2b(v[r]);
                    }
                }
            }
        }
    }
}

// ---------------- mean of Kp over all keys (fallback value), two-stage ----------------
__global__ void k_meanpart(const ushort* __restrict__ Kc, const int* __restrict__ koff,
                           float* __restrict__ part) {
    int b = blockIdx.x, ch = blockIdx.y;
    int d = threadIdx.x;
    int base = koff[b*8];
    float a0 = 0.f, a1 = 0.f;
    for (int t = ch*256; t < ch*256 + 256; ++t) {
        const ushort* row = Kc + (size_t)(base + t) * DD;
        a0 += b2f(row[d]); a1 += b2f(row[d + 256]);
    }
    part[((size_t)(b*8 + ch))*DD + d]       = a0;
    part[((size_t)(b*8 + ch))*DD + d + 256] = a1;
}
__global__ void k_meanfinal(const float* __restrict__ part, float* __restrict__ meanV) {
    int b = blockIdx.x; int d = threadIdx.x;
    float a0 = 0.f, a1 = 0.f;
    for (int ch = 0; ch < 8; ++ch) {
        a0 += part[((size_t)(b*8 + ch))*DD + d];
        a1 += part[((size_t)(b*8 + ch))*DD + d + 256];
    }
    meanV[b*DD + d]       = a0 * (1.0f/SKL);
    meanV[b*DD + d + 256] = a1 * (1.0f/SKL);
}

// ---------------- grouped scores S = Qc @ Kc^T (scale pre-folded into Qc) ----------------
__global__ __launch_bounds__(256) void k_scores_mfma(
        const ushort* __restrict__ Qc, const ushort* __restrict__ Kc,
        const int* __restrict__ qcnt, const int* __restrict__ kcnt,
        const int* __restrict__ qoff, const int* __restrict__ koff,
        const int* __restrict__ soff, const int* __restrict__ counts,
        const int* __restrict__ scl, float* __restrict__ S) {
    int tid = threadIdx.x, wid = tid >> 6, lane = tid & 63;
    int wr = wid >> 1, wc = wid & 1;
    int lr = lane & 15, lk = (lane >> 4) * 8;
    int cnt = counts[1];
    for (int slot = blockIdx.x; slot < cnt; slot += gridDim.x) {
        int e = scl[slot];
        int g = (e >> 10) & 31, qt = ((e >> 5) & 31) * 64, kt = (e & 31) * 64;
        int nq = qcnt[g], nk = kcnt[g];
        int qb = qoff[g], kb = koff[g];

        const ushort* ap[2];
#pragma unroll
        for (int t = 0; t < 2; ++t)
            ap[t] = Qc + (size_t)(qb + min(qt + wr*32 + t*16 + lr, nq - 1)) * DD + lk;
        const ushort* bp[2];
#pragma unroll
        for (int c = 0; c < 2; ++c)
            bp[c] = Kc + (size_t)(kb + min(kt + wc*32 + c*16 + lr, nk - 1)) * DD + lk;

        f32x4 acc[2][2];
#pragma unroll
        for (int t = 0; t < 2; ++t)
#pragma unroll
            for (int c = 0; c < 2; ++c) acc[t][c] = (f32x4){0.f, 0.f, 0.f, 0.f};

        short8v a[2], bb[2], an[2], bn[2];
#pragma unroll
        for (int t = 0; t < 2; ++t) a[t]  = *(const short8v*)(ap[t]);
#pragma unroll
        for (int c = 0; c < 2; ++c) bb[c] = *(const short8v*)(bp[c]);
        for (int d0 = 0; d0 < DD; d0 += 32) {
            int dn = d0 + 32;
            if (dn < DD) {
#pragma unroll
                for (int t = 0; t < 2; ++t) an[t] = *(const short8v*)(ap[t] + dn);
#pragma unroll
                for (int c = 0; c < 2; ++c) bn[c] = *(const short8v*)(bp[c] + dn);
            }
#pragma unroll
            for (int t = 0; t < 2; ++t)
#pragma unroll
                for (int c = 0; c < 2; ++c)
                    acc[t][c] = __builtin_amdgcn_mfma_f32_16x16x32_bf16(a[t], bb[c], acc[t][c], 0, 0, 0);
#pragma unroll
            for (int t = 0; t < 2; ++t) a[t] = an[t];
#pragma unroll
            for (int c = 0; c < 2; ++c) bb[c] = bn[c];
        }

        int sbase = soff[g];
        int rb = (lane >> 4) << 2;
#pragma unroll
        for (int t = 0; t < 2; ++t) {
#pragma unroll
            for (int r = 0; r < 4; ++r) {
                int gr = qt + wr*32 + t*16 + rb + r;
                if (gr >= nq) continue;
#pragma unroll
                for (int c = 0; c < 2; ++c) {
                    int gc = kt + wc*32 + c*16 + lr;
                    if (gc < nk) S[(size_t)sbase + (size_t)gr*nk + gc] = acc[t][c][r];
                }
            }
        }
    }
}

// ---------------- softmax rows -> bf16 probs, rows padded to mult of 32 ----------------
__global__ void k_softmax(const int* __restrict__ qcnt, const int* __restrict__ kcnt,
                          const int* __restrict__ soff, const int* __restrict__ pboff,
                          float* __restrict__ S, ushort* __restrict__ Pb) {
    int g = blockIdx.x;
    int nq = qcnt[g], nk = kcnt[g];
    int wid = threadIdx.x >> 6, lane = threadIdx.x & 63;
    int row = blockIdx.y * 16 + wid;
    if (nk == 0 || row >= nq) return;
    int nkp = (nk + 31) & ~31;
    float* p = S + (size_t)soff[g] + (size_t)row * nk;
    ushort* pr = Pb + (size_t)pboff[g] + (size_t)row * nkp;
    float mx = -3.4e38f;
    for (int c = lane; c < nk; c += 64) mx = fmaxf(mx, p[c]);
#pragma unroll
    for (int off = 32; off > 0; off >>= 1) mx = fmaxf(mx, __shfl_xor(mx, off));
    float sm = 0.f;
    for (int c = lane; c < nk; c += 64) { float e = expf(p[c] - mx); p[c] = e; sm += e; }
#pragma unroll
    for (int off = 32; off > 0; off >>= 1) sm += __shfl_xor(sm, off);
    float inv = 1.0f / sm;
    for (int c = lane; c < nkp; c += 64) {
        float v = (c < nk) ? p[c] * inv : 0.f;
        pr[c] = f2b(v);
    }
}

// ---------------- PV: O = P @ Kc via KcT, bf16 MFMA, epilogue += Q ----------------
__global__ __launch_bounds__(256) void k_pv_mfma(
        const ushort* __restrict__ Pb, const ushort* __restrict__ KcT,
        const float* __restrict__ Q,
        const int* __restrict__ qcnt, const int* __restrict__ kcnt,
        const int* __restrict__ tkoff, const int* __restrict__ pboff,
        const int* __restrict__ qlist, const int* __restrict__ counts,
        const int* __restrict__ pvl, float* __restrict__ out) {
    int tid = threadIdx.x, wid = tid >> 6, lane = tid & 63;
    int wr = wid >> 1, wc = wid & 1;
    int lr = lane & 15, lk = (lane >> 4) * 8;
    int cnt = counts[2];
    for (int slot = blockIdx.x; slot < cnt; slot += gridDim.x) {
        int e = pvl[slot];
        int g = e >> 5, qt = (e & 31) * 64;
        int nq = qcnt[g], nk = kcnt[g];
        int b = g >> 3;
        int nkp = (nk + 31) & ~31;
        int tk = tkoff[g], pbase = pboff[g];
        int dt = blockIdx.y * 128;

        const ushort* ap[2];
#pragma unroll
        for (int t = 0; t < 2; ++t)
            ap[t] = Pb + (size_t)pbase + (size_t)min(qt + wr*32 + t*16 + lr, nq - 1) * nkp + lk;
        int dcol[4];
        const ushort* bp[4];
#pragma unroll
        for (int c = 0; c < 4; ++c) {
            dcol[c] = dt + wc*64 + c*16 + lr;
            bp[c] = KcT + (size_t)tk + (size_t)dcol[c] * nkp + lk;
        }

        f32x4 acc[2][4];
#pragma unroll
        for (int t = 0; t < 2; ++t)
#pragma unroll
            for (int c = 0; c < 4; ++c) acc[t][c] = (f32x4){0.f, 0.f, 0.f, 0.f};

        for (int kk = 0; kk < nk; kk += 32) {
            short8v a[2], bb[4];
#pragma unroll
            for (int t = 0; t < 2; ++t) a[t] = *(const short8v*)(ap[t] + kk);
#pragma unroll
            for (int c = 0; c < 4; ++c) bb[c] = *(const short8v*)(bp[c] + kk);
#pragma unroll
            for (int t = 0; t < 2; ++t)
#pragma unroll
                for (int c = 0; c < 4; ++c)
                    acc[t][c] = __builtin_amdgcn_mfma_f32_16x16x32_bf16(a[t], bb[c], acc[t][c], 0, 0, 0);
        }

        int rb = (lane >> 4) << 2;
#pragma unroll
        for (int t = 0; t < 2; ++t) {
#pragma unroll
            for (int r = 0; r < 4; ++r) {
                int gr = qt + wr*32 + t*16 + rb + r;
                if (gr >= nq) continue;
                int qrow = qlist[g*SQL + gr];
                size_t obase = ((size_t)(b*SQL) + qrow) * DD;
#pragma unroll
                for (int c = 0; c < 4; ++c) {
                    size_t o = obase + dcol[c];
                    out[o] = acc[t][c][r] + Q[o];
                }
            }
        }
    }
}

// ---------------- fallback for groups with no keys: O = mean(Kp) + Q ----------------
__global__ void k_fallback(const float* __restrict__ Q, const float* __restrict__ meanV,
                           const int* __restrict__ qcnt, const int* __restrict__ kcnt,
                           const int* __restrict__ qlist, float* __restrict__ out) {
    int g = blockIdx.x;
    if (kcnt[g] != 0) return;
    int nq = qcnt[g]; int b = g >> 3;
    int r0 = blockIdx.y * 256;
    int rend = min(r0 + 256, nq);
    for (int r = r0; r < rend; ++r) {
        int qrow = qlist[g*SQL + r];
        size_t base = ((size_t)(b*SQL) + qrow) * DD;
        for (int d = threadIdx.x; d < DD; d += 256)
            out[base + d] = meanV[b*DD + d] + Q[base + d];
    }
}

extern "C" void kernel_launch(void* const* d_in, const int* in_sizes, int n_in,
                              void* d_out, int out_size, void* d_ws, size_t ws_size,
                              hipStream_t stream) {
    (void)in_sizes; (void)n_in; (void)out_size; (void)ws_size;
    const float* Q   = (const float*)d_in[0];
    const float* K   = (const float*)d_in[1];
    // d_in[2] (V) unused: Vp == Kp in the reference.
    const float* miu = (const float*)d_in[3];
    const float* Wq  = (const float*)d_in[4];
    const float* bq  = (const float*)d_in[5];
    const float* Wk  = (const float*)d_in[6];
    const float* bk  = (const float*)d_in[7];
    float* out = (float*)d_out;
    char* ws = (char*)d_ws;

    size_t off = 0;
    auto alloc = [&](size_t bytes) { size_t o = off; off += (bytes + 255) & ~(size_t)255; return o; };
    int*   aq     = (int*)  (ws + alloc((size_t)BB*SQL*4));
    int*   ak     = (int*)  (ws + alloc((size_t)BB*SKL*4));
    int*   qcnt   = (int*)  (ws + alloc(NG*4));
    int*   kcnt   = (int*)  (ws + alloc(NG*4));
    int*   soff   = (int*)  (ws + alloc((NG+1)*4));
    int*   pboff  = (int*)  (ws + alloc((NG+1)*4));
    int*   qoff   = (int*)  (ws + alloc((NG+1)*4));
    int*   koff   = (int*)  (ws + alloc((NG+1)*4));
    int*   tkoff  = (int*)  (ws + alloc((NG+1)*4));
    int*   counts = (int*)  (ws + alloc(16*4));
    int*   projl  = (int*)  (ws + alloc(PROJCAP*4));
    int*   scl    = (int*)  (ws + alloc(SCCAP*4));
    int*   pvl    = (int*)  (ws + alloc(PVCAP*4));
    int*   qlist  = (int*)  (ws + alloc((size_t)NG*SQL*4));
    int*   klist  = (int*)  (ws + alloc((size_t)NG*SKL*4));
    float* part   = (float*)(ws + alloc((size_t)BB*8*DD*4));
    float* meanV  = (float*)(ws + alloc((size_t)BB*DD*4));
    ushort* Qc    = (ushort*)(ws + alloc((size_t)BB*SQL*DD*2));
    ushort* Kc    = (ushort*)(ws + alloc((size_t)BB*SKL*DD*2));
    ushort* KcT   = (ushort*)(ws + alloc(KTCAP*2));
    ushort* Pb    = (ushort*)(ws + alloc((size_t)PCAP*2));
    // Union region (32 MB): bf16 staging Wqt|Wkt|XcQ|XcK (dead after proj), then S (f32).
    size_t uoff = alloc((size_t)SCAP*4);
    float* S     = (float*)(ws + uoff);
    ushort* Wqt  = (ushort*)(ws + uoff);
    ushort* Wkt  = Wqt  + (size_t)MM*DD*DD;
    ushort* XcQ  = Wkt  + (size_t)MM*DD*DD;
    ushort* XcK  = XcQ  + (size_t)BB*SQL*DD;

    k_route     <<<NTOK/4, 256, 0, stream>>>(Q, K, miu, aq, ak);
    k_compact   <<<NG*2, 64, 0, stream>>>(aq, ak, qcnt, kcnt, qlist, klist);
    k_soff      <<<1, 64, 0, stream>>>(qcnt, kcnt, soff, pboff, qoff, koff, tkoff,
                                       counts, projl, scl, pvl);
    k_cvtW      <<<dim3(16, 16, 16), dim3(32, 8), 0, stream>>>(Wq, Wk, Wqt, Wkt);
    k_gather    <<<dim3(64, 128), 256, 0, stream>>>(Q, K, qcnt, kcnt, qlist, klist,
                                                    qoff, koff, XcQ, XcK);
    k_proj_mfma <<<dim3(192, 4), 256, 0, stream>>>(XcQ, XcK, Wqt, Wkt, bq, bk,
                                                   qcnt, kcnt, qoff, koff,
                                                   tkoff, counts, projl, Qc, Kc, KcT);
    k_meanpart  <<<dim3(BB, 8), 256, 0, stream>>>(Kc, koff, part);
    k_meanfinal <<<BB, 256, 0, stream>>>(part, meanV);
    k_scores_mfma<<<1024, 256, 0, stream>>>(Qc, Kc, qcnt, kcnt, qoff, koff, soff,
                                            counts, scl, S);
    k_softmax   <<<dim3(NG, 128), 1024, 0, stream>>>(qcnt, kcnt, soff, pboff, S, Pb);
    k_pv_mfma   <<<dim3(256, 4), 256, 0, stream>>>(Pb, KcT, Q, qcnt, kcnt, tkoff, pboff,
                                                   qlist, counts, pvl, out);
    k_fallback  <<<dim3(NG, 8), 256, 0, stream>>>(Q, meanV, qcnt, kcnt, qlist, out);
}